// Round 1
// baseline (1261.516 us; speedup 1.0000x reference)
//
#include <hip/hip_runtime.h>
#include <math.h>

// ---------------------------------------------------------------------------
// Problem constants (fixed production sizes from the reference)
// ---------------------------------------------------------------------------
namespace {
constexpr int cB  = 64;
constexpr int cNQ = 32;
constexpr int cND = 512;
constexpr int cDIN = 64;
constexpr int cDD = 128;
constexpr int cKK = 16;
constexpr int cNd = cB * cND;   // 32768 data nodes
constexpr int cNq = cB * cNQ;   // 2048 query nodes
constexpr int cEd = cNd * 8;    // 262144 data edges
constexpr int cEq = cNq * 8;    // 16384 query edges
}

#define F4C(p) (*(const float4*)(p))
#define F4W(p) (*(float4*)(p))

// ---------------------------------------------------------------------------
// CSR construction
// ---------------------------------------------------------------------------
__global__ void gmn_count(const int* __restrict__ dst, int* __restrict__ cnt, int E) {
  int i = blockIdx.x * 256 + threadIdx.x;
  if (i < E) atomicAdd(&cnt[dst[i]], 1);
}

__global__ __launch_bounds__(1024) void gmn_scan(const int* __restrict__ cnt,
                                                 int* __restrict__ rp, int N) {
  __shared__ int sh[1024];
  int tid = threadIdx.x;
  int carry = 0;
  for (int base = 0; base < N; base += 1024) {
    int v = (base + tid < N) ? cnt[base + tid] : 0;
    sh[tid] = v;
    __syncthreads();
    for (int off = 1; off < 1024; off <<= 1) {
      int t = (tid >= off) ? sh[tid - off] : 0;
      __syncthreads();
      sh[tid] += t;
      __syncthreads();
    }
    if (base + tid < N) rp[base + tid] = carry + sh[tid] - v;  // exclusive
    carry += sh[1023];
    __syncthreads();
  }
}

__global__ void gmn_dinv(const int* __restrict__ cnt, float* __restrict__ dinv, int N) {
  int i = blockIdx.x * 256 + threadIdx.x;
  if (i < N) dinv[i] = 1.0f / sqrtf((float)(cnt[i] + 1));  // +1 self loop
}

__global__ void gmn_fill(const int* __restrict__ src, const int* __restrict__ dst,
                         const int* __restrict__ rp, int* __restrict__ cur,
                         int* __restrict__ col, int E) {
  int i = blockIdx.x * 256 + threadIdx.x;
  if (i < E) {
    int d = dst[i];
    int p = atomicAdd(&cur[d], 1);
    col[rp[d] + p] = src[i];
  }
}

// ---------------------------------------------------------------------------
// GCN dense part: H = X @ W   (X: [N,KD], W: [KD,128]); 64-row x 128-col tiles
// ---------------------------------------------------------------------------
template <int KD>
__global__ __launch_bounds__(256) void gmn_gemm(const float* __restrict__ X,
                                                const float* __restrict__ W,
                                                float* __restrict__ H) {
  __shared__ __attribute__((aligned(16))) float sh_xT[KD * 68];   // xT[d][r]
  __shared__ __attribute__((aligned(16))) float sh_w[KD * 128];   // w[d][c]
  int tid = threadIdx.x;
  int row0 = blockIdx.x * 64;
#pragma unroll
  for (int i = 0; i < 64 * KD / 256; ++i) {
    int j = tid + 256 * i;
    int r = j / KD, d = j % KD;
    sh_xT[d * 68 + r] = X[(row0 + r) * KD + d];
  }
#pragma unroll
  for (int i = 0; i < KD * 128 / 256; ++i) {
    int j = tid + 256 * i;
    sh_w[j] = W[j];
  }
  __syncthreads();
  int r0 = (tid >> 4) * 4;
  int c0 = (tid & 15) * 8;
  float acc[4][8];
#pragma unroll
  for (int a = 0; a < 4; ++a)
#pragma unroll
    for (int bb = 0; bb < 8; ++bb) acc[a][bb] = 0.0f;
#pragma unroll 4
  for (int d = 0; d < KD; ++d) {
    float4 xv = F4C(&sh_xT[d * 68 + r0]);
    float4 w0 = F4C(&sh_w[d * 128 + c0]);
    float4 w1 = F4C(&sh_w[d * 128 + c0 + 4]);
    float xa[4] = {xv.x, xv.y, xv.z, xv.w};
    float wa[8] = {w0.x, w0.y, w0.z, w0.w, w1.x, w1.y, w1.z, w1.w};
#pragma unroll
    for (int ri = 0; ri < 4; ++ri)
#pragma unroll
      for (int ci = 0; ci < 8; ++ci) acc[ri][ci] += xa[ri] * wa[ci];
  }
#pragma unroll
  for (int ri = 0; ri < 4; ++ri) {
    int idx = (row0 + r0 + ri) * 128 + c0;
    F4W(&H[idx])     = make_float4(acc[ri][0], acc[ri][1], acc[ri][2], acc[ri][3]);
    F4W(&H[idx + 4]) = make_float4(acc[ri][4], acc[ri][5], acc[ri][6], acc[ri][7]);
  }
}

// GCN aggregate: out[t,f] = relu(dinv[t]*(sum_edges h[s,f]*dinv[s] + h[t,f]*dinv[t]) + b[f])
__global__ __launch_bounds__(256) void gmn_gather(
    const float* __restrict__ h, const int* __restrict__ rp, const int* __restrict__ cnt,
    const int* __restrict__ col, const float* __restrict__ dinv,
    const float* __restrict__ bias, float* __restrict__ out) {
  int node = blockIdx.x * 2 + (threadIdx.x >> 7);
  int f = threadIdx.x & 127;
  float dt = dinv[node];
  float acc = h[node * 128 + f] * dt;  // self loop (x dt again below)
  int s0 = rp[node], c = cnt[node];
  for (int i = 0; i < c; ++i) {
    int s = col[s0 + i];
    acc += h[s * 128 + f] * dinv[s];
  }
  out[node * 128 + f] = fmaxf(acc * dt + bias[f], 0.0f);
}

// ---------------------------------------------------------------------------
// lq / ld: wave-per-8-rows dot products with Vn halves
// out[(b*16+k)*Rp + r] = sum_d Vn[k*256+voff+d] * M[(b*Rp+r)*128 + d]
// ---------------------------------------------------------------------------
__global__ __launch_bounds__(256) void gmn_rowdot(const float* __restrict__ M, int Rp,
                                                  const float* __restrict__ Vn, int voff,
                                                  float* __restrict__ out) {
  int wid = blockIdx.x * 4 + (threadIdx.x >> 6);
  int lane = threadIdx.x & 63;
  int G = Rp >> 3;  // groups of 8 rows per (b,k)
  int b = wid / (16 * G);
  int rem = wid - b * 16 * G;
  int k = rem / G;
  int r0 = (rem - k * G) * 8;
  float va = Vn[k * 256 + voff + lane];
  float vb = Vn[k * 256 + voff + 64 + lane];
  const float* base = M + (size_t)(b * Rp + r0) * 128;
  for (int i = 0; i < 8; ++i) {
    float s = va * base[i * 128 + lane] + vb * base[i * 128 + 64 + lane];
#pragma unroll
    for (int o = 32; o; o >>= 1) s += __shfl_xor(s, o, 64);
    if (lane == 0) out[(b * 16 + k) * Rp + r0 + i] = s;
  }
}

// ---------------------------------------------------------------------------
// attention logits: att[b,q,n] = (q[b,q,:]·d[b,n,:]) / sqrt(128)
// grid = B*4 blocks (128-n chunks), 256 threads, 4q x 4n register tiles
// ---------------------------------------------------------------------------
__global__ __launch_bounds__(256) void gmn_logits(const float* __restrict__ qlev,
                                                  const float* __restrict__ dlev,
                                                  float* __restrict__ att) {
  __shared__ __attribute__((aligned(16))) float sh_qT[128 * 36];   // qT[e][q]
  __shared__ __attribute__((aligned(16))) float sh_dT[128 * 132];  // dT[e][n]
  int tid = threadIdx.x;
  int b = blockIdx.x >> 2, nc = blockIdx.x & 3, n0 = nc * 128;
#pragma unroll
  for (int i = 0; i < 16; ++i) {
    int j = tid + 256 * i;
    int q = j >> 7, e = j & 127;
    sh_qT[e * 36 + q] = qlev[b * 4096 + j];
  }
#pragma unroll 4
  for (int i = 0; i < 64; ++i) {
    int j = tid + 256 * i;
    int n = j >> 7, e = j & 127;
    sh_dT[e * 132 + n] = dlev[b * 65536 + n0 * 128 + j];
  }
  __syncthreads();
  int q0 = (tid >> 5) * 4, x0 = (tid & 31) * 4;
  float bl[4][4];
#pragma unroll
  for (int a = 0; a < 4; ++a)
#pragma unroll
    for (int bb = 0; bb < 4; ++bb) bl[a][bb] = 0.0f;
#pragma unroll 8
  for (int e = 0; e < 128; ++e) {
    float4 qv = F4C(&sh_qT[e * 36 + q0]);
    float4 dv = F4C(&sh_dT[e * 132 + x0]);
    float qa[4] = {qv.x, qv.y, qv.z, qv.w};
    float da[4] = {dv.x, dv.y, dv.z, dv.w};
#pragma unroll
    for (int qi = 0; qi < 4; ++qi)
#pragma unroll
      for (int ni = 0; ni < 4; ++ni) bl[qi][ni] += qa[qi] * da[ni];
  }
  const float sc = 1.0f / sqrtf(128.0f);
#pragma unroll
  for (int qi = 0; qi < 4; ++qi) {
    int idx = ((b * 32 + q0 + qi) << 9) + n0 + x0;
#pragma unroll
    for (int ni = 0; ni < 4; ++ni) att[idx + ni] = bl[qi][ni] * sc;
  }
}

// ---------------------------------------------------------------------------
// rowwise softmax over 512 cols, in place. grid = rows, 256 threads.
// ---------------------------------------------------------------------------
__global__ __launch_bounds__(256) void gmn_softmax_rows(float* __restrict__ p) {
  __shared__ float sh[8];
  int tid = threadIdx.x;
  float* r = p + (size_t)blockIdx.x * 512;
  float v0 = r[tid], v1 = r[tid + 256];
  float m = fmaxf(v0, v1);
#pragma unroll
  for (int o = 32; o; o >>= 1) m = fmaxf(m, __shfl_xor(m, o, 64));
  if ((tid & 63) == 0) sh[tid >> 6] = m;
  __syncthreads();
  m = fmaxf(fmaxf(sh[0], sh[1]), fmaxf(sh[2], sh[3]));
  float e0 = expf(v0 - m), e1 = expf(v1 - m);
  float s = e0 + e1;
#pragma unroll
  for (int o = 32; o; o >>= 1) s += __shfl_xor(s, o, 64);
  if ((tid & 63) == 0) sh[4 + (tid >> 6)] = s;
  __syncthreads();
  s = sh[4] + sh[5] + sh[6] + sh[7];
  float inv = 1.0f / s;
  r[tid] = e0 * inv;
  r[tid + 256] = e1 * inv;
}

// ---------------------------------------------------------------------------
// The fused NTN level kernel. grid = B*4 (128-n chunks), 256 threads.
// Loops all 16 k in-block: qW = q[b]@Wn[k] (Wn staged via LDS), bil = qW@d^T,
// he = sigmoid(bil+lq+ld+bn)*att; accumulates e_raw (cw-weighted) and the
// final-conv contribution (wk-weighted) in registers -> no atomics.
// ---------------------------------------------------------------------------
__global__ __launch_bounds__(256) void gmn_level(
    const float* __restrict__ qlev, const float* __restrict__ dlev,
    const float* __restrict__ Wn, const float* __restrict__ bn,
    const float* __restrict__ cw, const float* __restrict__ cb,
    const float* __restrict__ att, const float* __restrict__ lqb,
    const float* __restrict__ ldb, const float* __restrict__ w_end,
    int o1, int o2, float* __restrict__ Ebuf, float* __restrict__ accb,
    int do_facc) {
  __shared__ __attribute__((aligned(16))) float sh_qT[128 * 36];    // q^T [d][q]
  __shared__ __attribute__((aligned(16))) float sh_qwT[128 * 36];   // qW^T [e][q]
  __shared__ __attribute__((aligned(16))) float sh_dT[128 * 132];   // d^T [e][n]
  __shared__ __attribute__((aligned(16))) float sh_wn[32 * 132];    // Wn chunk [dd][e]
  int tid = threadIdx.x;
  int b = blockIdx.x >> 2, nc = blockIdx.x & 3, n0 = nc * 128;
#pragma unroll
  for (int i = 0; i < 16; ++i) {
    int j = tid + 256 * i;
    int q = j >> 7, d = j & 127;
    sh_qT[d * 36 + q] = qlev[b * 4096 + j];
  }
#pragma unroll 4
  for (int i = 0; i < 64; ++i) {
    int j = tid + 256 * i;
    int n = j >> 7, e = j & 127;
    sh_dT[e * 132 + n] = dlev[b * 65536 + n0 * 128 + j];
  }
  __syncthreads();

  int q0 = (tid >> 5) * 4;   // q tile base
  int x0 = (tid & 31) * 4;   // e tile base (qW phase) == n tile base (bil phase)

  float attv[4][4];
#pragma unroll
  for (int qi = 0; qi < 4; ++qi) {
    int idx = ((b * 32 + q0 + qi) << 9) + n0 + x0;
#pragma unroll
    for (int ni = 0; ni < 4; ++ni) attv[qi][ni] = att[idx + ni];
  }
  float eacc[4][4], facc[4][4];
#pragma unroll
  for (int a = 0; a < 4; ++a)
#pragma unroll
    for (int bb = 0; bb < 4; ++bb) { eacc[a][bb] = 0.0f; facc[a][bb] = 0.0f; }

  for (int k = 0; k < 16; ++k) {
    const float* wk_src = Wn + k * 16384;
    float a[4][4];
#pragma unroll
    for (int aa = 0; aa < 4; ++aa)
#pragma unroll
      for (int bb = 0; bb < 4; ++bb) a[aa][bb] = 0.0f;
    for (int dc = 0; dc < 128; dc += 32) {
#pragma unroll
      for (int i = 0; i < 4; ++i) {               // stage 32 rows of Wn[k]
        int j4 = tid + 256 * i;                   // 1024 float4 = 32*128 floats
        int dd = j4 >> 5, e4 = (j4 & 31) * 4;
        F4W(&sh_wn[dd * 132 + e4]) = F4C(&wk_src[(dc + dd) * 128 + e4]);
      }
      __syncthreads();
#pragma unroll 8
      for (int dd = 0; dd < 32; ++dd) {
        float4 qv = F4C(&sh_qT[(dc + dd) * 36 + q0]);
        float4 wv = F4C(&sh_wn[dd * 132 + x0]);
        float qa[4] = {qv.x, qv.y, qv.z, qv.w};
        float wa[4] = {wv.x, wv.y, wv.z, wv.w};
#pragma unroll
        for (int qi = 0; qi < 4; ++qi)
#pragma unroll
          for (int ei = 0; ei < 4; ++ei) a[qi][ei] += qa[qi] * wa[ei];
      }
      __syncthreads();
    }
#pragma unroll
    for (int ei = 0; ei < 4; ++ei)
      F4W(&sh_qwT[(x0 + ei) * 36 + q0]) =
          make_float4(a[0][ei], a[1][ei], a[2][ei], a[3][ei]);
    __syncthreads();

    float bl[4][4];
#pragma unroll
    for (int aa = 0; aa < 4; ++aa)
#pragma unroll
      for (int bb = 0; bb < 4; ++bb) bl[aa][bb] = 0.0f;
#pragma unroll 8
    for (int e = 0; e < 128; ++e) {
      float4 qv = F4C(&sh_qwT[e * 36 + q0]);
      float4 dv = F4C(&sh_dT[e * 132 + x0]);
      float qa[4] = {qv.x, qv.y, qv.z, qv.w};
      float da[4] = {dv.x, dv.y, dv.z, dv.w};
#pragma unroll
      for (int qi = 0; qi < 4; ++qi)
#pragma unroll
        for (int ni = 0; ni < 4; ++ni) bl[qi][ni] += qa[qi] * da[ni];
    }

    float bnk = bn[k], cwk = cw[k];
    float wkk = 0.0f;
    if (do_facc) {
      wkk = w_end[o1 + k];
      if (o2 >= 0) wkk += w_end[o2 + k];
    }
    float ldl[4];
    {
      int lidx = (b * 16 + k) * 512 + n0 + x0;
#pragma unroll
      for (int ni = 0; ni < 4; ++ni) ldl[ni] = ldb[lidx + ni];
    }
#pragma unroll
    for (int qi = 0; qi < 4; ++qi) {
      float lqv = lqb[(b * 16 + k) * 32 + q0 + qi];
#pragma unroll
      for (int ni = 0; ni < 4; ++ni) {
        float z = bl[qi][ni] + lqv + ldl[ni] + bnk;
        float he = attv[qi][ni] / (1.0f + expf(-z));
        eacc[qi][ni] += cwk * he;
        facc[qi][ni] += wkk * he;
      }
    }
  }

  float cbv = cb[0];
#pragma unroll
  for (int qi = 0; qi < 4; ++qi) {
    int idx = ((b * 32 + q0 + qi) << 9) + n0 + x0;
#pragma unroll
    for (int ni = 0; ni < 4; ++ni) Ebuf[idx + ni] = eacc[qi][ni] + cbv;
    if (do_facc) {
#pragma unroll
      for (int ni = 0; ni < 4; ++ni) accb[idx + ni] += facc[qi][ni];
    }
  }
}

// acc += w_end[widx] * (do_sm ? softmax(E_row) : E_row)
__global__ __launch_bounds__(256) void gmn_combine(const float* __restrict__ Ebuf,
                                                   float* __restrict__ accb,
                                                   const float* __restrict__ w_end,
                                                   int widx, int do_sm) {
  __shared__ float sh[8];
  int tid = threadIdx.x;
  size_t base = (size_t)blockIdx.x * 512;
  float w = w_end[widx];
  float v0 = Ebuf[base + tid], v1 = Ebuf[base + tid + 256];
  if (do_sm) {
    float m = fmaxf(v0, v1);
#pragma unroll
    for (int o = 32; o; o >>= 1) m = fmaxf(m, __shfl_xor(m, o, 64));
    if ((tid & 63) == 0) sh[tid >> 6] = m;
    __syncthreads();
    m = fmaxf(fmaxf(sh[0], sh[1]), fmaxf(sh[2], sh[3]));
    float e0 = expf(v0 - m), e1 = expf(v1 - m);
    float s = e0 + e1;
#pragma unroll
    for (int o = 32; o; o >>= 1) s += __shfl_xor(s, o, 64);
    if ((tid & 63) == 0) sh[4 + (tid >> 6)] = s;
    __syncthreads();
    s = sh[4] + sh[5] + sh[6] + sh[7];
    float inv = 1.0f / s;
    v0 = e0 * inv;
    v1 = e1 * inv;
  }
  accb[base + tid] += w * v0;
  accb[base + tid + 256] += w * v1;
}

// out = softmax(acc + b_end) rowwise
__global__ __launch_bounds__(256) void gmn_final(const float* __restrict__ accb,
                                                 const float* __restrict__ b_end,
                                                 float* __restrict__ out) {
  __shared__ float sh[8];
  int tid = threadIdx.x;
  size_t base = (size_t)blockIdx.x * 512;
  float be = b_end[0];
  float v0 = accb[base + tid] + be, v1 = accb[base + tid + 256] + be;
  float m = fmaxf(v0, v1);
#pragma unroll
  for (int o = 32; o; o >>= 1) m = fmaxf(m, __shfl_xor(m, o, 64));
  if ((tid & 63) == 0) sh[tid >> 6] = m;
  __syncthreads();
  m = fmaxf(fmaxf(sh[0], sh[1]), fmaxf(sh[2], sh[3]));
  float e0 = expf(v0 - m), e1 = expf(v1 - m);
  float s = e0 + e1;
#pragma unroll
  for (int o = 32; o; o >>= 1) s += __shfl_xor(s, o, 64);
  if ((tid & 63) == 0) sh[4 + (tid >> 6)] = s;
  __syncthreads();
  s = sh[4] + sh[5] + sh[6] + sh[7];
  float inv = 1.0f / s;
  out[base + tid] = e0 * inv;
  out[base + tid + 256] = e1 * inv;
}

// ---------------------------------------------------------------------------
// Host orchestration
// ---------------------------------------------------------------------------
extern "C" void kernel_launch(void* const* d_in, const int* in_sizes, int n_in,
                              void* d_out, int out_size, void* d_ws, size_t ws_size,
                              hipStream_t stream) {
  (void)in_sizes; (void)n_in; (void)out_size; (void)ws_size;
  const float* x_d = (const float*)d_in[0];
  const float* x_q = (const float*)d_in[1];
  const int* ei_d = (const int*)d_in[2];
  const int* ei_q = (const int*)d_in[3];
  const float* W1 = (const float*)d_in[6];
  const float* b1 = (const float*)d_in[7];
  const float* W2 = (const float*)d_in[8];
  const float* b2 = (const float*)d_in[9];
  const float* W3 = (const float*)d_in[10];
  const float* b3 = (const float*)d_in[11];
  const float* Wn[3] = {(const float*)d_in[12], (const float*)d_in[17], (const float*)d_in[22]};
  const float* Vn[3] = {(const float*)d_in[13], (const float*)d_in[18], (const float*)d_in[23]};
  const float* bn[3] = {(const float*)d_in[14], (const float*)d_in[19], (const float*)d_in[24]};
  const float* cw[3] = {(const float*)d_in[15], (const float*)d_in[20], (const float*)d_in[25]};
  const float* cb[3] = {(const float*)d_in[16], (const float*)d_in[21], (const float*)d_in[26]};
  const float* w_end = (const float*)d_in[27];
  const float* b_end = (const float*)d_in[28];
  float* out = (float*)d_out;

  char* wsp = (char*)d_ws;
  auto alloc = [&](size_t nbytes) {
    void* p = (void*)wsp;
    wsp += (nbytes + 255) & ~(size_t)255;
    return p;
  };
  float* dinv_d = (float*)alloc(cNd * 4);
  float* dinv_q = (float*)alloc(cNq * 4);
  int* cnt_d = (int*)alloc(cNd * 4);
  int* cnt_q = (int*)alloc(cNq * 4);
  int* rp_d = (int*)alloc(cNd * 4);
  int* rp_q = (int*)alloc(cNq * 4);
  int* cur_d = (int*)alloc(cNd * 4);
  int* cur_q = (int*)alloc(cNq * 4);
  int* col_d = (int*)alloc((size_t)cEd * 4);
  int* col_q = (int*)alloc((size_t)cEq * 4);
  float* dA = (float*)alloc((size_t)cNd * 128 * 4);
  float* dB = (float*)alloc((size_t)cNd * 128 * 4);
  float* q1 = (float*)alloc((size_t)cNq * 128 * 4);
  float* q2 = (float*)alloc((size_t)cNq * 128 * 4);
  float* q3 = (float*)alloc((size_t)cNq * 128 * 4);
  float* htmp = (float*)alloc((size_t)cNd * 128 * 4);
  float* att = (float*)alloc((size_t)cB * cNQ * cND * 4);
  float* Ebuf = (float*)alloc((size_t)cB * cNQ * cND * 4);
  float* accb = (float*)alloc((size_t)cB * cNQ * cND * 4);
  float* lqb = (float*)alloc((size_t)cB * 16 * 32 * 4);
  float* ldb = (float*)alloc((size_t)cB * 16 * 512 * 4);

  const int* src_d = ei_d;
  const int* dst_d = ei_d + cEd;
  const int* src_q = ei_q;
  const int* dst_q = ei_q + cEq;

  hipMemsetAsync(cnt_d, 0, cNd * 4, stream);
  hipMemsetAsync(cnt_q, 0, cNq * 4, stream);
  hipMemsetAsync(cur_d, 0, cNd * 4, stream);
  hipMemsetAsync(cur_q, 0, cNq * 4, stream);
  hipMemsetAsync(accb, 0, (size_t)cB * cNQ * cND * 4, stream);

  // --- CSR + dinv ---
  gmn_count<<<cEd / 256, 256, 0, stream>>>(dst_d, cnt_d, cEd);
  gmn_count<<<cEq / 256, 256, 0, stream>>>(dst_q, cnt_q, cEq);
  gmn_scan<<<1, 1024, 0, stream>>>(cnt_d, rp_d, cNd);
  gmn_scan<<<1, 1024, 0, stream>>>(cnt_q, rp_q, cNq);
  gmn_dinv<<<cNd / 256, 256, 0, stream>>>(cnt_d, dinv_d, cNd);
  gmn_dinv<<<cNq / 256, 256, 0, stream>>>(cnt_q, dinv_q, cNq);
  gmn_fill<<<cEd / 256, 256, 0, stream>>>(src_d, dst_d, rp_d, cur_d, col_d, cEd);
  gmn_fill<<<cEq / 256, 256, 0, stream>>>(src_q, dst_q, rp_q, cur_q, col_q, cEq);

  // --- query GCN chain (q1,q2,q3) ---
  gmn_gemm<64><<<cNq / 64, 256, 0, stream>>>(x_q, W1, htmp);
  gmn_gather<<<cNq / 2, 256, 0, stream>>>(htmp, rp_q, cnt_q, col_q, dinv_q, b1, q1);
  gmn_gemm<128><<<cNq / 64, 256, 0, stream>>>(q1, W2, htmp);
  gmn_gather<<<cNq / 2, 256, 0, stream>>>(htmp, rp_q, cnt_q, col_q, dinv_q, b2, q2);
  gmn_gemm<128><<<cNq / 64, 256, 0, stream>>>(q2, W3, htmp);
  gmn_gather<<<cNq / 2, 256, 0, stream>>>(htmp, rp_q, cnt_q, col_q, dinv_q, b3, q3);

  // --- data GCN layer 1 -> dA ---
  gmn_gemm<64><<<cNd / 64, 256, 0, stream>>>(x_d, W1, htmp);
  gmn_gather<<<cNd / 2, 256, 0, stream>>>(htmp, rp_d, cnt_d, col_d, dinv_d, b1, dA);

  // --- level 1 (e1 softmaxed; he1 dead -> no facc) ---
  gmn_rowdot<<<cB * 16 * 4 / 4, 256, 0, stream>>>(q1, 32, Vn[0], 0, lqb);
  gmn_rowdot<<<cB * 16 * 64 / 4, 256, 0, stream>>>(dA, 512, Vn[0], 128, ldb);
  gmn_logits<<<cB * 4, 256, 0, stream>>>(q1, dA, att);
  gmn_softmax_rows<<<cB * cNQ, 256, 0, stream>>>(att);
  gmn_level<<<cB * 4, 256, 0, stream>>>(q1, dA, Wn[0], bn[0], cw[0], cb[0], att, lqb,
                                        ldb, w_end, 0, -1, Ebuf, accb, 0);
  gmn_combine<<<cB * cNQ, 256, 0, stream>>>(Ebuf, accb, w_end, 0, 1);

  // --- data GCN layer 2 -> dB ---
  gmn_gemm<128><<<cNd / 64, 256, 0, stream>>>(dA, W2, htmp);
  gmn_gather<<<cNd / 2, 256, 0, stream>>>(htmp, rp_d, cnt_d, col_d, dinv_d, b2, dB);

  // --- level 2 (e2 RAW into final concat; he2 channels 19..34) ---
  gmn_rowdot<<<cB * 16 * 4 / 4, 256, 0, stream>>>(q2, 32, Vn[1], 0, lqb);
  gmn_rowdot<<<cB * 16 * 64 / 4, 256, 0, stream>>>(dB, 512, Vn[1], 128, ldb);
  gmn_logits<<<cB * 4, 256, 0, stream>>>(q2, dB, att);
  gmn_softmax_rows<<<cB * cNQ, 256, 0, stream>>>(att);
  gmn_level<<<cB * 4, 256, 0, stream>>>(q2, dB, Wn[1], bn[1], cw[1], cb[1], att, lqb,
                                        ldb, w_end, 19, -1, Ebuf, accb, 1);
  gmn_combine<<<cB * cNQ, 256, 0, stream>>>(Ebuf, accb, w_end, 1, 0);

  // --- data GCN layer 3 -> dA ---
  gmn_gemm<128><<<cNd / 64, 256, 0, stream>>>(dB, W3, htmp);
  gmn_gather<<<cNd / 2, 256, 0, stream>>>(htmp, rp_d, cnt_d, col_d, dinv_d, b3, dA);

  // --- level 3 (e3 softmaxed; he3 appears at channels 3..18 AND 35..50) ---
  gmn_rowdot<<<cB * 16 * 4 / 4, 256, 0, stream>>>(q3, 32, Vn[2], 0, lqb);
  gmn_rowdot<<<cB * 16 * 64 / 4, 256, 0, stream>>>(dA, 512, Vn[2], 128, ldb);
  gmn_logits<<<cB * 4, 256, 0, stream>>>(q3, dA, att);
  gmn_softmax_rows<<<cB * cNQ, 256, 0, stream>>>(att);
  gmn_level<<<cB * 4, 256, 0, stream>>>(q3, dA, Wn[2], bn[2], cw[2], cb[2], att, lqb,
                                        ldb, w_end, 3, 35, Ebuf, accb, 1);
  gmn_combine<<<cB * cNQ, 256, 0, stream>>>(Ebuf, accb, w_end, 2, 1);

  // --- final 1x1 conv bias + softmax over data nodes ---
  gmn_final<<<cB * cNQ, 256, 0, stream>>>(accb, b_end, out);
}

// Round 2
// 709.265 us; speedup vs baseline: 1.7786x; 1.7786x over previous
//
#include <hip/hip_runtime.h>
#include <math.h>

// ---------------------------------------------------------------------------
// Problem constants (fixed production sizes from the reference)
// ---------------------------------------------------------------------------
namespace {
constexpr int cB  = 64;
constexpr int cNQ = 32;
constexpr int cND = 512;
constexpr int cNd = cB * cND;   // 32768 data nodes
constexpr int cNq = cB * cNQ;   // 2048 query nodes
constexpr int cEd = cNd * 8;    // 262144 data edges
constexpr int cEq = cNq * 8;    // 16384 query edges
}

#define F4C(p) (*(const float4*)(p))
#define F4W(p) (*(float4*)(p))

typedef __attribute__((ext_vector_type(8))) __bf16 bf16x8;
typedef __attribute__((ext_vector_type(4))) float floatx4;

__device__ __forceinline__ ushort f2bf(float f) {
  union { float f; unsigned u; } v;
  v.f = f;
  unsigned u = v.u;
  unsigned r = (u + 0x7fffu + ((u >> 16) & 1u)) >> 16;
  return (ushort)r;
}

// ---------------------------------------------------------------------------
// CSR construction
// ---------------------------------------------------------------------------
__global__ void gmn_count(const int* __restrict__ dst, int* __restrict__ cnt, int E) {
  int i = blockIdx.x * 256 + threadIdx.x;
  if (i < E) atomicAdd(&cnt[dst[i]], 1);
}

// hierarchical exclusive scan over N = gridDim.x * 1024 elements
__global__ __launch_bounds__(1024) void gmn_scan_local(const int* __restrict__ cnt,
                                                       int* __restrict__ rp,
                                                       int* __restrict__ bsum) {
  __shared__ int sh[1024];
  int tid = threadIdx.x;
  int base = blockIdx.x * 1024;
  int v = cnt[base + tid];
  sh[tid] = v;
  __syncthreads();
  for (int off = 1; off < 1024; off <<= 1) {
    int t = (tid >= off) ? sh[tid - off] : 0;
    __syncthreads();
    sh[tid] += t;
    __syncthreads();
  }
  rp[base + tid] = sh[tid] - v;  // exclusive
  if (tid == 1023) bsum[blockIdx.x] = sh[1023];
}

__global__ void gmn_scan_off(int* __restrict__ bsum, int nb) {
  int acc = 0;
  for (int i = 0; i < nb; ++i) { int t = bsum[i]; bsum[i] = acc; acc += t; }
}

__global__ __launch_bounds__(1024) void gmn_scan_add(int* __restrict__ rp,
                                                     const int* __restrict__ bsum) {
  rp[blockIdx.x * 1024 + threadIdx.x] += bsum[blockIdx.x];
}

__global__ void gmn_dinv(const int* __restrict__ cnt, float* __restrict__ dinv, int N) {
  int i = blockIdx.x * 256 + threadIdx.x;
  if (i < N) dinv[i] = 1.0f / sqrtf((float)(cnt[i] + 1));  // +1 self loop
}

__global__ void gmn_fill(const int* __restrict__ src, const int* __restrict__ dst,
                         const int* __restrict__ rp, int* __restrict__ cur,
                         int* __restrict__ col, int E) {
  int i = blockIdx.x * 256 + threadIdx.x;
  if (i < E) {
    int d = dst[i];
    int p = atomicAdd(&cur[d], 1);
    col[rp[d] + p] = src[i];
  }
}

// ---------------------------------------------------------------------------
// GCN dense part: H = X @ W   (X: [N,KD], W: [KD,128]); 64-row x 128-col tiles
// ---------------------------------------------------------------------------
template <int KD>
__global__ __launch_bounds__(256) void gmn_gemm(const float* __restrict__ X,
                                                const float* __restrict__ W,
                                                float* __restrict__ H) {
  __shared__ __attribute__((aligned(16))) float sh_xT[KD * 68];   // xT[d][r]
  __shared__ __attribute__((aligned(16))) float sh_w[KD * 128];   // w[d][c]
  int tid = threadIdx.x;
  int row0 = blockIdx.x * 64;
#pragma unroll
  for (int i = 0; i < 64 * KD / 256; ++i) {
    int j = tid + 256 * i;
    int r = j / KD, d = j % KD;
    sh_xT[d * 68 + r] = X[(row0 + r) * KD + d];
  }
#pragma unroll
  for (int i = 0; i < KD * 128 / 256; ++i) {
    int j = tid + 256 * i;
    sh_w[j] = W[j];
  }
  __syncthreads();
  int r0 = (tid >> 4) * 4;
  int c0 = (tid & 15) * 8;
  float acc[4][8];
#pragma unroll
  for (int a = 0; a < 4; ++a)
#pragma unroll
    for (int bb = 0; bb < 8; ++bb) acc[a][bb] = 0.0f;
#pragma unroll 4
  for (int d = 0; d < KD; ++d) {
    float4 xv = F4C(&sh_xT[d * 68 + r0]);
    float4 w0 = F4C(&sh_w[d * 128 + c0]);
    float4 w1 = F4C(&sh_w[d * 128 + c0 + 4]);
    float xa[4] = {xv.x, xv.y, xv.z, xv.w};
    float wa[8] = {w0.x, w0.y, w0.z, w0.w, w1.x, w1.y, w1.z, w1.w};
#pragma unroll
    for (int ri = 0; ri < 4; ++ri)
#pragma unroll
      for (int ci = 0; ci < 8; ++ci) acc[ri][ci] += xa[ri] * wa[ci];
  }
#pragma unroll
  for (int ri = 0; ri < 4; ++ri) {
    int idx = (row0 + r0 + ri) * 128 + c0;
    F4W(&H[idx])     = make_float4(acc[ri][0], acc[ri][1], acc[ri][2], acc[ri][3]);
    F4W(&H[idx + 4]) = make_float4(acc[ri][4], acc[ri][5], acc[ri][6], acc[ri][7]);
  }
}

// GCN aggregate: out[t,f] = relu(dinv[t]*(sum_edges h[s,f]*dinv[s] + h[t,f]*dinv[t]) + b[f])
// Optionally writes a bf16 copy (for the MFMA level kernel).
__global__ __launch_bounds__(256) void gmn_gather(
    const float* __restrict__ h, const int* __restrict__ rp, const int* __restrict__ cnt,
    const int* __restrict__ col, const float* __restrict__ dinv,
    const float* __restrict__ bias, float* __restrict__ out,
    ushort* __restrict__ outbf, int do_bf) {
  int node = blockIdx.x * 2 + (threadIdx.x >> 7);
  int f = threadIdx.x & 127;
  float dt = dinv[node];
  float acc = h[node * 128 + f] * dt;  // self loop (x dt again below)
  int s0 = rp[node], c = cnt[node];
  for (int i = 0; i < c; ++i) {
    int s = col[s0 + i];
    acc += h[s * 128 + f] * dinv[s];
  }
  float r = fmaxf(acc * dt + bias[f], 0.0f);
  out[node * 128 + f] = r;
  if (do_bf) outbf[node * 128 + f] = f2bf(r);
}

// ---------------------------------------------------------------------------
// qW precompute: qW[b,k,q,e] = sum_d q[b,q,d] * Wn[k,d,e]  (f32 math, bf16 out)
// grid = B*K = 1024 blocks, 256 threads.
// ---------------------------------------------------------------------------
__global__ __launch_bounds__(256) void gmn_qw(const float* __restrict__ qlev,
                                              const float* __restrict__ Wn,
                                              ushort* __restrict__ qw) {
  __shared__ __attribute__((aligned(16))) float sh_qT[128 * 36];  // qT[d][q]
  __shared__ __attribute__((aligned(16))) float sh_w[32 * 132];   // Wn chunk [dd][e]
  int tid = threadIdx.x;
  int b = blockIdx.x >> 4, k = blockIdx.x & 15;
#pragma unroll
  for (int i = 0; i < 16; ++i) {
    int j = tid + 256 * i;
    int q = j >> 7, d = j & 127;
    sh_qT[d * 36 + q] = qlev[b * 4096 + j];
  }
  int q0 = (tid >> 5) * 4, e0 = (tid & 31) * 4;
  float acc[4][4];
#pragma unroll
  for (int a = 0; a < 4; ++a)
#pragma unroll
    for (int bb = 0; bb < 4; ++bb) acc[a][bb] = 0.0f;
  for (int dc = 0; dc < 128; dc += 32) {
    if (dc) __syncthreads();
#pragma unroll
    for (int i = 0; i < 4; ++i) {
      int j4 = tid + 256 * i;
      int dd = j4 >> 5, e4 = (j4 & 31) * 4;
      F4W(&sh_w[dd * 132 + e4]) = F4C(&Wn[k * 16384 + (dc + dd) * 128 + e4]);
    }
    __syncthreads();
#pragma unroll 8
    for (int dd = 0; dd < 32; ++dd) {
      float4 qv = F4C(&sh_qT[(dc + dd) * 36 + q0]);
      float4 wv = F4C(&sh_w[dd * 132 + e0]);
      float qa[4] = {qv.x, qv.y, qv.z, qv.w};
      float wa[4] = {wv.x, wv.y, wv.z, wv.w};
#pragma unroll
      for (int qi = 0; qi < 4; ++qi)
#pragma unroll
        for (int ei = 0; ei < 4; ++ei) acc[qi][ei] += qa[qi] * wa[ei];
    }
  }
#pragma unroll
  for (int qi = 0; qi < 4; ++qi) {
    ushort4 o;
    o.x = f2bf(acc[qi][0]); o.y = f2bf(acc[qi][1]);
    o.z = f2bf(acc[qi][2]); o.w = f2bf(acc[qi][3]);
    *(ushort4*)&qw[((size_t)b << 16) + (k << 12) + (q0 + qi) * 128 + e0] = o;
  }
}

// ---------------------------------------------------------------------------
// rowdot over all 16 k with single row read:
// out[(b*16+k)*Rp + r] = sum_e Vn[k*256+voff+e] * M[row*128+e], Rp = 1<<rsh
// grid = rows/16, 256 threads (thread = (row in 16-group, k)).
// ---------------------------------------------------------------------------
__global__ __launch_bounds__(256) void gmn_rowdot16(const float* __restrict__ M, int rsh,
                                                    const float* __restrict__ Vn, int voff,
                                                    float* __restrict__ out) {
  __shared__ float sh_r[16 * 132];
  __shared__ float sh_v[16 * 132];
  int tid = threadIdx.x;
  int g0 = blockIdx.x * 16;
#pragma unroll
  for (int i = 0; i < 8; ++i) {
    int j = tid + 256 * i;
    int a = j >> 7, e = j & 127;
    sh_r[a * 132 + e] = M[(size_t)(g0 + a) * 128 + e];
    sh_v[a * 132 + e] = Vn[a * 256 + voff + e];
  }
  __syncthreads();
  int r = tid & 15, k = tid >> 4;
  float s = 0.0f;
#pragma unroll 8
  for (int e = 0; e < 128; ++e) s += sh_r[r * 132 + e] * sh_v[k * 132 + e];
  int g = g0 + r;
  int b = g >> rsh;
  int rr = g & ((1 << rsh) - 1);
  out[((b * 16 + k) << rsh) + rr] = s;
}

// ---------------------------------------------------------------------------
// attention logits: att[b,q,n] = (q[b,q,:]·d[b,n,:]) / sqrt(128)
// ---------------------------------------------------------------------------
__global__ __launch_bounds__(256) void gmn_logits(const float* __restrict__ qlev,
                                                  const float* __restrict__ dlev,
                                                  float* __restrict__ att) {
  __shared__ __attribute__((aligned(16))) float sh_qT[128 * 36];   // qT[e][q]
  __shared__ __attribute__((aligned(16))) float sh_dT[128 * 132];  // dT[e][n]
  int tid = threadIdx.x;
  int b = blockIdx.x >> 2, nc = blockIdx.x & 3, n0 = nc * 128;
#pragma unroll
  for (int i = 0; i < 16; ++i) {
    int j = tid + 256 * i;
    int q = j >> 7, e = j & 127;
    sh_qT[e * 36 + q] = qlev[b * 4096 + j];
  }
#pragma unroll 4
  for (int i = 0; i < 64; ++i) {
    int j = tid + 256 * i;
    int n = j >> 7, e = j & 127;
    sh_dT[e * 132 + n] = dlev[b * 65536 + n0 * 128 + j];
  }
  __syncthreads();
  int q0 = (tid >> 5) * 4, x0 = (tid & 31) * 4;
  float bl[4][4];
#pragma unroll
  for (int a = 0; a < 4; ++a)
#pragma unroll
    for (int bb = 0; bb < 4; ++bb) bl[a][bb] = 0.0f;
#pragma unroll 8
  for (int e = 0; e < 128; ++e) {
    float4 qv = F4C(&sh_qT[e * 36 + q0]);
    float4 dv = F4C(&sh_dT[e * 132 + x0]);
    float qa[4] = {qv.x, qv.y, qv.z, qv.w};
    float da[4] = {dv.x, dv.y, dv.z, dv.w};
#pragma unroll
    for (int qi = 0; qi < 4; ++qi)
#pragma unroll
      for (int ni = 0; ni < 4; ++ni) bl[qi][ni] += qa[qi] * da[ni];
  }
  const float sc = 1.0f / sqrtf(128.0f);
#pragma unroll
  for (int qi = 0; qi < 4; ++qi) {
    int idx = ((b * 32 + q0 + qi) << 9) + n0 + x0;
#pragma unroll
    for (int ni = 0; ni < 4; ++ni) att[idx + ni] = bl[qi][ni] * sc;
  }
}

// ---------------------------------------------------------------------------
// rowwise softmax over 512 cols, in place. grid = rows, 256 threads.
// ---------------------------------------------------------------------------
__global__ __launch_bounds__(256) void gmn_softmax_rows(float* __restrict__ p) {
  __shared__ float sh[8];
  int tid = threadIdx.x;
  float* r = p + (size_t)blockIdx.x * 512;
  float v0 = r[tid], v1 = r[tid + 256];
  float m = fmaxf(v0, v1);
#pragma unroll
  for (int o = 32; o; o >>= 1) m = fmaxf(m, __shfl_xor(m, o, 64));
  if ((tid & 63) == 0) sh[tid >> 6] = m;
  __syncthreads();
  m = fmaxf(fmaxf(sh[0], sh[1]), fmaxf(sh[2], sh[3]));
  float e0 = expf(v0 - m), e1 = expf(v1 - m);
  float s = e0 + e1;
#pragma unroll
  for (int o = 32; o; o >>= 1) s += __shfl_xor(s, o, 64);
  if ((tid & 63) == 0) sh[4 + (tid >> 6)] = s;
  __syncthreads();
  s = sh[4] + sh[5] + sh[6] + sh[7];
  float inv = 1.0f / s;
  r[tid] = e0 * inv;
  r[tid + 256] = e1 * inv;
}

// ---------------------------------------------------------------------------
// MFMA NTN level kernel. grid = B*8 (64-n chunks), 256 threads = 4 waves.
// Wave owns 16-n tile; per k: bil = qW[b,k] @ d^T via mfma_f32_16x16x32_bf16
// (A[m=lane&15][k=quad*8+j], B[k=quad*8+j][n=lane&15], C col=lane&15,
// row=quad*4+reg). Zero LDS, zero barriers; fragments straight from L1.
// Epilogue in f32 registers accumulates e_raw (cw) and final-conv (wk) sums.
// ---------------------------------------------------------------------------
__global__ __launch_bounds__(256) void gmn_level_mfma(
    const ushort* __restrict__ qw, const ushort* __restrict__ dbf,
    const float* __restrict__ att, const float* __restrict__ lqb,
    const float* __restrict__ ldb, const float* __restrict__ bn,
    const float* __restrict__ cw, const float* __restrict__ cb,
    const float* __restrict__ w_end, int o1, int o2, int do_facc,
    float* __restrict__ Ebuf, float* __restrict__ accb) {
  int tid = threadIdx.x;
  int wave = tid >> 6, lane = tid & 63;
  int b = blockIdx.x >> 3, nc = blockIdx.x & 7;
  int col = lane & 15, quad = lane >> 4;
  int n = nc * 64 + wave * 16 + col;
  const ushort* dptr = dbf + (((size_t)(b * 512 + n)) << 7) + quad * 8;
  const ushort* qwb = qw + ((size_t)b << 16);
  floatx4 eacc[2], facc[2];
  float attv[2][4];
#pragma unroll
  for (int t = 0; t < 2; ++t) {
#pragma unroll
    for (int r = 0; r < 4; ++r) {
      eacc[t][r] = 0.0f;
      facc[t][r] = 0.0f;
      attv[t][r] = att[((b * 32 + t * 16 + quad * 4 + r) << 9) + n];
    }
  }
  float cbv = cb[0];
  for (int k = 0; k < 16; ++k) {
    floatx4 bil[2];
#pragma unroll
    for (int t = 0; t < 2; ++t)
#pragma unroll
      for (int r = 0; r < 4; ++r) bil[t][r] = 0.0f;
    const ushort* qk = qwb + (k << 12) + quad * 8;
#pragma unroll
    for (int kc = 0; kc < 4; ++kc) {
      bf16x8 bf = *(const bf16x8*)(dptr + kc * 32);
      bf16x8 a0 = *(const bf16x8*)(qk + (col << 7) + kc * 32);
      bf16x8 a1 = *(const bf16x8*)(qk + ((col + 16) << 7) + kc * 32);
      bil[0] = __builtin_amdgcn_mfma_f32_16x16x32_bf16(a0, bf, bil[0], 0, 0, 0);
      bil[1] = __builtin_amdgcn_mfma_f32_16x16x32_bf16(a1, bf, bil[1], 0, 0, 0);
    }
    float ldv = ldb[((b * 16 + k) << 9) + n];
    float bnk = bn[k], cwk = cw[k];
    float wkk = 0.0f;
    if (do_facc) {
      wkk = w_end[o1 + k];
      if (o2 >= 0) wkk += w_end[o2 + k];
    }
#pragma unroll
    for (int t = 0; t < 2; ++t) {
#pragma unroll
      for (int r = 0; r < 4; ++r) {
        float lqv = lqb[(b * 16 + k) * 32 + t * 16 + quad * 4 + r];
        float z = bil[t][r] + lqv + ldv + bnk;
        float he = attv[t][r] / (1.0f + expf(-z));
        eacc[t][r] = eacc[t][r] + cwk * he;
        facc[t][r] = facc[t][r] + wkk * he;
      }
    }
  }
#pragma unroll
  for (int t = 0; t < 2; ++t) {
#pragma unroll
    for (int r = 0; r < 4; ++r) {
      int idx = ((b * 32 + t * 16 + quad * 4 + r) << 9) + n;
      Ebuf[idx] = eacc[t][r] + cbv;
      if (do_facc) accb[idx] += facc[t][r];
    }
  }
}

// acc += w_end[widx] * (do_sm ? softmax(E_row) : E_row)
__global__ __launch_bounds__(256) void gmn_combine(const float* __restrict__ Ebuf,
                                                   float* __restrict__ accb,
                                                   const float* __restrict__ w_end,
                                                   int widx, int do_sm) {
  __shared__ float sh[8];
  int tid = threadIdx.x;
  size_t base = (size_t)blockIdx.x * 512;
  float w = w_end[widx];
  float v0 = Ebuf[base + tid], v1 = Ebuf[base + tid + 256];
  if (do_sm) {
    float m = fmaxf(v0, v1);
#pragma unroll
    for (int o = 32; o; o >>= 1) m = fmaxf(m, __shfl_xor(m, o, 64));
    if ((tid & 63) == 0) sh[tid >> 6] = m;
    __syncthreads();
    m = fmaxf(fmaxf(sh[0], sh[1]), fmaxf(sh[2], sh[3]));
    float e0 = expf(v0 - m), e1 = expf(v1 - m);
    float s = e0 + e1;
#pragma unroll
    for (int o = 32; o; o >>= 1) s += __shfl_xor(s, o, 64);
    if ((tid & 63) == 0) sh[4 + (tid >> 6)] = s;
    __syncthreads();
    s = sh[4] + sh[5] + sh[6] + sh[7];
    float inv = 1.0f / s;
    v0 = e0 * inv;
    v1 = e1 * inv;
  }
  accb[base + tid] += w * v0;
  accb[base + tid + 256] += w * v1;
}

// out = softmax(acc + b_end) rowwise
__global__ __launch_bounds__(256) void gmn_final(const float* __restrict__ accb,
                                                 const float* __restrict__ b_end,
                                                 float* __restrict__ out) {
  __shared__ float sh[8];
  int tid = threadIdx.x;
  size_t base = (size_t)blockIdx.x * 512;
  float be = b_end[0];
  float v0 = accb[base + tid] + be, v1 = accb[base + tid + 256] + be;
  float m = fmaxf(v0, v1);
#pragma unroll
  for (int o = 32; o; o >>= 1) m = fmaxf(m, __shfl_xor(m, o, 64));
  if ((tid & 63) == 0) sh[tid >> 6] = m;
  __syncthreads();
  m = fmaxf(fmaxf(sh[0], sh[1]), fmaxf(sh[2], sh[3]));
  float e0 = expf(v0 - m), e1 = expf(v1 - m);
  float s = e0 + e1;
#pragma unroll
  for (int o = 32; o; o >>= 1) s += __shfl_xor(s, o, 64);
  if ((tid & 63) == 0) sh[4 + (tid >> 6)] = s;
  __syncthreads();
  s = sh[4] + sh[5] + sh[6] + sh[7];
  float inv = 1.0f / s;
  out[base + tid] = e0 * inv;
  out[base + tid + 256] = e1 * inv;
}

// ---------------------------------------------------------------------------
// Host orchestration
// ---------------------------------------------------------------------------
extern "C" void kernel_launch(void* const* d_in, const int* in_sizes, int n_in,
                              void* d_out, int out_size, void* d_ws, size_t ws_size,
                              hipStream_t stream) {
  (void)in_sizes; (void)n_in; (void)out_size; (void)ws_size;
  const float* x_d = (const float*)d_in[0];
  const float* x_q = (const float*)d_in[1];
  const int* ei_d = (const int*)d_in[2];
  const int* ei_q = (const int*)d_in[3];
  const float* W1 = (const float*)d_in[6];
  const float* b1 = (const float*)d_in[7];
  const float* W2 = (const float*)d_in[8];
  const float* b2 = (const float*)d_in[9];
  const float* W3 = (const float*)d_in[10];
  const float* b3 = (const float*)d_in[11];
  const float* Wn[3] = {(const float*)d_in[12], (const float*)d_in[17], (const float*)d_in[22]};
  const float* Vn[3] = {(const float*)d_in[13], (const float*)d_in[18], (const float*)d_in[23]};
  const float* bn[3] = {(const float*)d_in[14], (const float*)d_in[19], (const float*)d_in[24]};
  const float* cw[3] = {(const float*)d_in[15], (const float*)d_in[20], (const float*)d_in[25]};
  const float* cb[3] = {(const float*)d_in[16], (const float*)d_in[21], (const float*)d_in[26]};
  const float* w_end = (const float*)d_in[27];
  const float* b_end = (const float*)d_in[28];
  float* out = (float*)d_out;

  char* wsp = (char*)d_ws;
  auto alloc = [&](size_t nbytes) {
    void* p = (void*)wsp;
    wsp += (nbytes + 255) & ~(size_t)255;
    return p;
  };
  float* dinv_d = (float*)alloc(cNd * 4);
  float* dinv_q = (float*)alloc(cNq * 4);
  int* cnt_d = (int*)alloc(cNd * 4);
  int* cnt_q = (int*)alloc(cNq * 4);
  int* rp_d = (int*)alloc(cNd * 4);
  int* rp_q = (int*)alloc(cNq * 4);
  int* cur_d = (int*)alloc(cNd * 4);
  int* cur_q = (int*)alloc(cNq * 4);
  int* col_d = (int*)alloc((size_t)cEd * 4);
  int* col_q = (int*)alloc((size_t)cEq * 4);
  int* bsum = (int*)alloc(64 * 4);
  float* dA = (float*)alloc((size_t)cNd * 128 * 4);
  float* dB = (float*)alloc((size_t)cNd * 128 * 4);
  float* q1 = (float*)alloc((size_t)cNq * 128 * 4);
  float* q2 = (float*)alloc((size_t)cNq * 128 * 4);
  float* q3 = (float*)alloc((size_t)cNq * 128 * 4);
  float* htmp = (float*)alloc((size_t)cNd * 128 * 4);
  float* att = (float*)alloc((size_t)cB * cNQ * cND * 4);
  float* Ebuf = (float*)alloc((size_t)cB * cNQ * cND * 4);
  float* accb = (float*)alloc((size_t)cB * cNQ * cND * 4);
  float* lqb = (float*)alloc((size_t)cB * 16 * 32 * 4);
  float* ldb = (float*)alloc((size_t)cB * 16 * 512 * 4);
  ushort* qwbuf = (ushort*)alloc((size_t)cB * 16 * 32 * 128 * 2);  // 8.4 MB bf16
  ushort* dbf = (ushort*)alloc((size_t)cNd * 128 * 2);             // 8.4 MB bf16

  const int* src_d = ei_d;
  const int* dst_d = ei_d + cEd;
  const int* src_q = ei_q;
  const int* dst_q = ei_q + cEq;

  hipMemsetAsync(cnt_d, 0, cNd * 4, stream);
  hipMemsetAsync(cnt_q, 0, cNq * 4, stream);
  hipMemsetAsync(cur_d, 0, cNd * 4, stream);
  hipMemsetAsync(cur_q, 0, cNq * 4, stream);
  hipMemsetAsync(accb, 0, (size_t)cB * cNQ * cND * 4, stream);

  // --- CSR + dinv ---
  gmn_count<<<cEd / 256, 256, 0, stream>>>(dst_d, cnt_d, cEd);
  gmn_count<<<cEq / 256, 256, 0, stream>>>(dst_q, cnt_q, cEq);
  gmn_scan_local<<<cNd / 1024, 1024, 0, stream>>>(cnt_d, rp_d, bsum);
  gmn_scan_off<<<1, 1, 0, stream>>>(bsum, cNd / 1024);
  gmn_scan_add<<<cNd / 1024, 1024, 0, stream>>>(rp_d, bsum);
  gmn_scan_local<<<cNq / 1024, 1024, 0, stream>>>(cnt_q, rp_q, bsum);
  gmn_scan_off<<<1, 1, 0, stream>>>(bsum, cNq / 1024);
  gmn_scan_add<<<cNq / 1024, 1024, 0, stream>>>(rp_q, bsum);
  gmn_dinv<<<cNd / 256, 256, 0, stream>>>(cnt_d, dinv_d, cNd);
  gmn_dinv<<<cNq / 256, 256, 0, stream>>>(cnt_q, dinv_q, cNq);
  gmn_fill<<<cEd / 256, 256, 0, stream>>>(src_d, dst_d, rp_d, cur_d, col_d, cEd);
  gmn_fill<<<cEq / 256, 256, 0, stream>>>(src_q, dst_q, rp_q, cur_q, col_q, cEq);

  // --- query GCN chain (q1,q2,q3) ---
  gmn_gemm<64><<<cNq / 64, 256, 0, stream>>>(x_q, W1, htmp);
  gmn_gather<<<cNq / 2, 256, 0, stream>>>(htmp, rp_q, cnt_q, col_q, dinv_q, b1, q1, dbf, 0);
  gmn_gemm<128><<<cNq / 64, 256, 0, stream>>>(q1, W2, htmp);
  gmn_gather<<<cNq / 2, 256, 0, stream>>>(htmp, rp_q, cnt_q, col_q, dinv_q, b2, q2, dbf, 0);
  gmn_gemm<128><<<cNq / 64, 256, 0, stream>>>(q2, W3, htmp);
  gmn_gather<<<cNq / 2, 256, 0, stream>>>(htmp, rp_q, cnt_q, col_q, dinv_q, b3, q3, dbf, 0);

  // --- data GCN layer 1 -> dA (+bf16) ---
  gmn_gemm<64><<<cNd / 64, 256, 0, stream>>>(x_d, W1, htmp);
  gmn_gather<<<cNd / 2, 256, 0, stream>>>(htmp, rp_d, cnt_d, col_d, dinv_d, b1, dA, dbf, 1);

  // --- level 1 (e1 softmaxed; he1 dead -> no facc) ---
  gmn_qw<<<cB * 16, 256, 0, stream>>>(q1, Wn[0], qwbuf);
  gmn_rowdot16<<<cNq / 16, 256, 0, stream>>>(q1, 5, Vn[0], 0, lqb);
  gmn_rowdot16<<<cNd / 16, 256, 0, stream>>>(dA, 9, Vn[0], 128, ldb);
  gmn_logits<<<cB * 4, 256, 0, stream>>>(q1, dA, att);
  gmn_softmax_rows<<<cB * cNQ, 256, 0, stream>>>(att);
  gmn_level_mfma<<<cB * 8, 256, 0, stream>>>(qwbuf, dbf, att, lqb, ldb, bn[0], cw[0],
                                             cb[0], w_end, 0, -1, 0, Ebuf, accb);
  gmn_combine<<<cB * cNQ, 256, 0, stream>>>(Ebuf, accb, w_end, 0, 1);

  // --- data GCN layer 2 -> dB (+bf16) ---
  gmn_gemm<128><<<cNd / 64, 256, 0, stream>>>(dA, W2, htmp);
  gmn_gather<<<cNd / 2, 256, 0, stream>>>(htmp, rp_d, cnt_d, col_d, dinv_d, b2, dB, dbf, 1);

  // --- level 2 (e2 RAW into final concat; he2 channels 19..34) ---
  gmn_qw<<<cB * 16, 256, 0, stream>>>(q2, Wn[1], qwbuf);
  gmn_rowdot16<<<cNq / 16, 256, 0, stream>>>(q2, 5, Vn[1], 0, lqb);
  gmn_rowdot16<<<cNd / 16, 256, 0, stream>>>(dB, 9, Vn[1], 128, ldb);
  gmn_logits<<<cB * 4, 256, 0, stream>>>(q2, dB, att);
  gmn_softmax_rows<<<cB * cNQ, 256, 0, stream>>>(att);
  gmn_level_mfma<<<cB * 8, 256, 0, stream>>>(qwbuf, dbf, att, lqb, ldb, bn[1], cw[1],
                                             cb[1], w_end, 19, -1, 1, Ebuf, accb);
  gmn_combine<<<cB * cNQ, 256, 0, stream>>>(Ebuf, accb, w_end, 1, 0);

  // --- data GCN layer 3 -> dA (+bf16) ---
  gmn_gemm<128><<<cNd / 64, 256, 0, stream>>>(dB, W3, htmp);
  gmn_gather<<<cNd / 2, 256, 0, stream>>>(htmp, rp_d, cnt_d, col_d, dinv_d, b3, dA, dbf, 1);

  // --- level 3 (e3 softmaxed; he3 at channels 3..18 AND 35..50) ---
  gmn_qw<<<cB * 16, 256, 0, stream>>>(q3, Wn[2], qwbuf);
  gmn_rowdot16<<<cNq / 16, 256, 0, stream>>>(q3, 5, Vn[2], 0, lqb);
  gmn_rowdot16<<<cNd / 16, 256, 0, stream>>>(dA, 9, Vn[2], 128, ldb);
  gmn_logits<<<cB * 4, 256, 0, stream>>>(q3, dA, att);
  gmn_softmax_rows<<<cB * cNQ, 256, 0, stream>>>(att);
  gmn_level_mfma<<<cB * 8, 256, 0, stream>>>(qwbuf, dbf, att, lqb, ldb, bn[2], cw[2],
                                             cb[2], w_end, 3, 35, 1, Ebuf, accb);
  gmn_combine<<<cB * cNQ, 256, 0, stream>>>(Ebuf, accb, w_end, 2, 1);

  // --- final 1x1 conv bias + softmax over data nodes ---
  gmn_final<<<cB * cNQ, 256, 0, stream>>>(accb, b_end, out);
}

// Round 3
// 521.707 us; speedup vs baseline: 2.4181x; 1.3595x over previous
//
#include <hip/hip_runtime.h>
#include <math.h>

// ---------------------------------------------------------------------------
// Problem constants (fixed production sizes from the reference)
// ---------------------------------------------------------------------------
namespace {
constexpr int cB  = 64;
constexpr int cNQ = 32;
constexpr int cND = 512;
constexpr int cNd = cB * cND;   // 32768 data nodes
constexpr int cNq = cB * cNQ;   // 2048 query nodes
constexpr int cEd = cNd * 8;    // 262144 data edges
constexpr int cEq = cNq * 8;    // 16384 query edges
}

#define F4C(p) (*(const float4*)(p))
#define F4W(p) (*(float4*)(p))

typedef __attribute__((ext_vector_type(8))) __bf16 bf16x8;
typedef __attribute__((ext_vector_type(4))) float floatx4;

__device__ __forceinline__ ushort f2bf(float f) {
  union { float f; unsigned u; } v;
  v.f = f;
  unsigned u = v.u;
  unsigned r = (u + 0x7fffu + ((u >> 16) & 1u)) >> 16;
  return (ushort)r;
}
__device__ __forceinline__ float bf2f(ushort u) {
  union { unsigned u; float f; } v;
  v.u = ((unsigned)u) << 16;
  return v.f;
}
__device__ __forceinline__ float4 us4f4(ushort4 u) {
  return make_float4(bf2f(u.x), bf2f(u.y), bf2f(u.z), bf2f(u.w));
}
__device__ __forceinline__ ushort4 f4us4(float4 f) {
  ushort4 o;
  o.x = f2bf(f.x); o.y = f2bf(f.y); o.z = f2bf(f.z); o.w = f2bf(f.w);
  return o;
}

// ---------------------------------------------------------------------------
// Conversions
// ---------------------------------------------------------------------------
__global__ void gmn_cvt(const float* __restrict__ in, ushort* __restrict__ out, int N4) {
  int i = blockIdx.x * 256 + threadIdx.x;
  if (i < N4) *(ushort4*)(out + i * 4) = f4us4(F4C(in + (size_t)i * 4));
}

// out[bt][c][r] = bf16(in[bt][r][c]);  R,C multiples of 32
__global__ __launch_bounds__(256) void gmn_t2bf(const float* __restrict__ in,
                                                ushort* __restrict__ out, int R, int C) {
  __shared__ float tile[32][33];
  int tilesR = R >> 5, tilesC = C >> 5;
  int bt = blockIdx.x / (tilesR * tilesC);
  int rem = blockIdx.x - bt * tilesR * tilesC;
  int tr = rem / tilesC, tc = rem - tr * tilesC;
  int tx = threadIdx.x & 31, ty = threadIdx.x >> 5;
  const float* ib = in + (size_t)bt * R * C;
  ushort* ob = out + (size_t)bt * R * C;
#pragma unroll
  for (int i = 0; i < 4; ++i)
    tile[ty + i * 8][tx] = ib[(tr * 32 + ty + i * 8) * C + tc * 32 + tx];
  __syncthreads();
#pragma unroll
  for (int i = 0; i < 4; ++i)
    ob[(size_t)(tc * 32 + ty + i * 8) * R + tr * 32 + tx] = f2bf(tile[tx][ty + i * 8]);
}

// ---------------------------------------------------------------------------
// CSR construction
// ---------------------------------------------------------------------------
__global__ void gmn_count(const int* __restrict__ dst, int* __restrict__ cnt, int E) {
  int i = blockIdx.x * 256 + threadIdx.x;
  if (i < E) atomicAdd(&cnt[dst[i]], 1);
}

__global__ __launch_bounds__(1024) void gmn_scan_local(const int* __restrict__ cnt,
                                                       int* __restrict__ rp,
                                                       int* __restrict__ bsum) {
  __shared__ int sh[1024];
  int tid = threadIdx.x;
  int base = blockIdx.x * 1024;
  int v = cnt[base + tid];
  sh[tid] = v;
  __syncthreads();
  for (int off = 1; off < 1024; off <<= 1) {
    int t = (tid >= off) ? sh[tid - off] : 0;
    __syncthreads();
    sh[tid] += t;
    __syncthreads();
  }
  rp[base + tid] = sh[tid] - v;  // exclusive
  if (tid == 1023) bsum[blockIdx.x] = sh[1023];
}

__global__ void gmn_scan_off(int* __restrict__ bsum, int nb) {
  int l = threadIdx.x;  // 64 threads
  int v = (l < nb) ? bsum[l] : 0;
  int orig = v;
#pragma unroll
  for (int off = 1; off < 64; off <<= 1) {
    int t = __shfl_up(v, off, 64);
    if (l >= off) v += t;
  }
  if (l < nb) bsum[l] = v - orig;  // exclusive
}

__global__ __launch_bounds__(1024) void gmn_scan_add(int* __restrict__ rp,
                                                     const int* __restrict__ bsum) {
  rp[blockIdx.x * 1024 + threadIdx.x] += bsum[blockIdx.x];
}

__global__ void gmn_dinv(const int* __restrict__ cnt, float* __restrict__ dinv, int N) {
  int i = blockIdx.x * 256 + threadIdx.x;
  if (i < N) dinv[i] = 1.0f / sqrtf((float)(cnt[i] + 1));  // +1 self loop
}

__global__ void gmn_fill(const int* __restrict__ src, const int* __restrict__ dst,
                         const int* __restrict__ rp, int* __restrict__ cur,
                         int* __restrict__ col, int E) {
  int i = blockIdx.x * 256 + threadIdx.x;
  if (i < E) {
    int d = dst[i];
    int p = atomicAdd(&cur[d], 1);
    col[rp[d] + p] = src[i];
  }
}

// ---------------------------------------------------------------------------
// GCN dense: H[n][c] = bf16( dinv[n] * sum_d X[n][d] * W[d][c] )  via MFMA.
// X bf16 [N][KD], WT bf16 [128][KD]. grid N/64, 256 thr (4 waves x 16 rows).
// ---------------------------------------------------------------------------
template <int KD>
__global__ __launch_bounds__(256) void gmn_gemm_mfma(const ushort* __restrict__ X,
                                                     const ushort* __restrict__ WT,
                                                     const float* __restrict__ dinv,
                                                     ushort* __restrict__ H) {
  int tid = threadIdx.x;
  int wave = tid >> 6, lane = tid & 63;
  int col = lane & 15, quad = lane >> 4;
  int m0 = blockIdx.x * 64 + wave * 16;
  floatx4 acc[8];
#pragma unroll
  for (int ct = 0; ct < 8; ++ct)
#pragma unroll
    for (int r = 0; r < 4; ++r) acc[ct][r] = 0.0f;
#pragma unroll
  for (int kc = 0; kc < KD / 32; ++kc) {
    bf16x8 a = *(const bf16x8*)(X + (size_t)(m0 + col) * KD + kc * 32 + quad * 8);
#pragma unroll
    for (int ct = 0; ct < 8; ++ct) {
      bf16x8 b = *(const bf16x8*)(WT + (size_t)(ct * 16 + col) * KD + kc * 32 + quad * 8);
      acc[ct] = __builtin_amdgcn_mfma_f32_16x16x32_bf16(a, b, acc[ct], 0, 0, 0);
    }
  }
  float sc[4];
#pragma unroll
  for (int r = 0; r < 4; ++r) sc[r] = dinv[m0 + quad * 4 + r];
#pragma unroll
  for (int ct = 0; ct < 8; ++ct)
#pragma unroll
    for (int r = 0; r < 4; ++r)
      H[(size_t)(m0 + quad * 4 + r) * 128 + ct * 16 + col] = f2bf(acc[ct][r] * sc[r]);
}

// ---------------------------------------------------------------------------
// GCN aggregate from pre-scaled bf16 rows:
// out[t] = relu(dinv[t]*(hs[t] + sum_s hs[s]) + bias). 32 lanes per node.
// ---------------------------------------------------------------------------
__global__ __launch_bounds__(256) void gmn_gather_bf(
    const ushort* __restrict__ hs, const int* __restrict__ rp,
    const int* __restrict__ cnt, const int* __restrict__ col,
    const float* __restrict__ dinv, const float* __restrict__ bias,
    ushort* __restrict__ outbf, float* __restrict__ outf, int do_f) {
  int tid = threadIdx.x;
  int node = blockIdx.x * 8 + (tid >> 5);
  int l = tid & 31;
  int c = cnt[node], s0 = rp[node];
  float dt = dinv[node];
  float4 acc = us4f4(*(const ushort4*)(hs + (size_t)node * 128 + l * 4));
  int cm = c < 32 ? c : 32;
  for (int j0 = 0; j0 < cm; j0 += 8) {
    int ss[8];
    ushort4 v[8];
#pragma unroll
    for (int t = 0; t < 8; ++t) {
      int jj = j0 + t;
      ss[t] = col[s0 + (jj < c ? jj : c - 1)];
    }
#pragma unroll
    for (int t = 0; t < 8; ++t)
      v[t] = *(const ushort4*)(hs + (size_t)ss[t] * 128 + l * 4);
#pragma unroll
    for (int t = 0; t < 8; ++t) {
      if (j0 + t < cm) {
        float4 f = us4f4(v[t]);
        acc.x += f.x; acc.y += f.y; acc.z += f.z; acc.w += f.w;
      }
    }
  }
  for (int j = 32; j < c; ++j) {  // essentially never taken
    int s = col[s0 + j];
    float4 f = us4f4(*(const ushort4*)(hs + (size_t)s * 128 + l * 4));
    acc.x += f.x; acc.y += f.y; acc.z += f.z; acc.w += f.w;
  }
  float4 bv = F4C(bias + l * 4);
  float4 r;
  r.x = fmaxf(acc.x * dt + bv.x, 0.0f);
  r.y = fmaxf(acc.y * dt + bv.y, 0.0f);
  r.z = fmaxf(acc.z * dt + bv.z, 0.0f);
  r.w = fmaxf(acc.w * dt + bv.w, 0.0f);
  *(ushort4*)(outbf + (size_t)node * 128 + l * 4) = f4us4(r);
  if (do_f) F4W(outf + (size_t)node * 128 + l * 4) = r;
}

// ---------------------------------------------------------------------------
// qW[b,k] = q[b] @ Wn[k]  (bf16 MFMA, bf16 out). grid B*16, 4 waves.
// wnT layout: [k][e][d].
// ---------------------------------------------------------------------------
__global__ __launch_bounds__(256) void gmn_qw_mfma(const ushort* __restrict__ qbf,
                                                   const ushort* __restrict__ wnT,
                                                   ushort* __restrict__ qw) {
  int tid = threadIdx.x;
  int wave = tid >> 6, lane = tid & 63;
  int col = lane & 15, quad = lane >> 4;
  int b = blockIdx.x >> 4, k = blockIdx.x & 15;
  int et0 = wave * 2;
  floatx4 acc[2][2];
#pragma unroll
  for (int qt = 0; qt < 2; ++qt)
#pragma unroll
    for (int ei = 0; ei < 2; ++ei)
#pragma unroll
      for (int r = 0; r < 4; ++r) acc[qt][ei][r] = 0.0f;
#pragma unroll
  for (int kc = 0; kc < 4; ++kc) {
    bf16x8 a0 = *(const bf16x8*)(qbf + (size_t)(b * 32 + col) * 128 + kc * 32 + quad * 8);
    bf16x8 a1 = *(const bf16x8*)(qbf + (size_t)(b * 32 + 16 + col) * 128 + kc * 32 + quad * 8);
#pragma unroll
    for (int ei = 0; ei < 2; ++ei) {
      bf16x8 bf = *(const bf16x8*)(wnT + (size_t)(k * 128 + (et0 + ei) * 16 + col) * 128 +
                                   kc * 32 + quad * 8);
      acc[0][ei] = __builtin_amdgcn_mfma_f32_16x16x32_bf16(a0, bf, acc[0][ei], 0, 0, 0);
      acc[1][ei] = __builtin_amdgcn_mfma_f32_16x16x32_bf16(a1, bf, acc[1][ei], 0, 0, 0);
    }
  }
#pragma unroll
  for (int qt = 0; qt < 2; ++qt)
#pragma unroll
    for (int ei = 0; ei < 2; ++ei)
#pragma unroll
      for (int r = 0; r < 4; ++r)
        qw[((size_t)(b * 16 + k) << 12) + (qt * 16 + quad * 4 + r) * 128 +
           (et0 + ei) * 16 + col] = f2bf(acc[qt][ei][r]);
}

// ---------------------------------------------------------------------------
// attention logits via MFMA: att[b,q,n] = (q·d)/sqrt(128). grid B*8, 4 waves.
// ---------------------------------------------------------------------------
__global__ __launch_bounds__(256) void gmn_logits_mfma(const ushort* __restrict__ qbf,
                                                       const ushort* __restrict__ dbf,
                                                       float* __restrict__ att) {
  int tid = threadIdx.x;
  int wave = tid >> 6, lane = tid & 63;
  int col = lane & 15, quad = lane >> 4;
  int b = blockIdx.x >> 3, nc = blockIdx.x & 7;
  int n = nc * 64 + wave * 16 + col;
  floatx4 acc[2];
#pragma unroll
  for (int qt = 0; qt < 2; ++qt)
#pragma unroll
    for (int r = 0; r < 4; ++r) acc[qt][r] = 0.0f;
#pragma unroll
  for (int kc = 0; kc < 4; ++kc) {
    bf16x8 bf = *(const bf16x8*)(dbf + ((size_t)(b * 512 + n) << 7) + kc * 32 + quad * 8);
    bf16x8 a0 = *(const bf16x8*)(qbf + (size_t)(b * 32 + col) * 128 + kc * 32 + quad * 8);
    bf16x8 a1 = *(const bf16x8*)(qbf + (size_t)(b * 32 + 16 + col) * 128 + kc * 32 + quad * 8);
    acc[0] = __builtin_amdgcn_mfma_f32_16x16x32_bf16(a0, bf, acc[0], 0, 0, 0);
    acc[1] = __builtin_amdgcn_mfma_f32_16x16x32_bf16(a1, bf, acc[1], 0, 0, 0);
  }
  const float sc = 1.0f / sqrtf(128.0f);
#pragma unroll
  for (int qt = 0; qt < 2; ++qt)
#pragma unroll
    for (int r = 0; r < 4; ++r)
      att[((size_t)(b * 32 + qt * 16 + quad * 4 + r) << 9) + n] = acc[qt][r] * sc;
}

// ---------------------------------------------------------------------------
// ld[b,k,n] = sum_d dbf[b,n,d] * Vn[k][128+d]  via MFMA. grid cB*2, 4 waves.
// vnbf: [16][256] bf16 (full Vn row; we use second half).
// ---------------------------------------------------------------------------
__global__ __launch_bounds__(256) void gmn_ld_mfma(const ushort* __restrict__ dbf,
                                                   const ushort* __restrict__ vnbf,
                                                   float* __restrict__ ldb) {
  int tid = threadIdx.x;
  int wave = tid >> 6, lane = tid & 63;
  int col = lane & 15, quad = lane >> 4;
  int b = blockIdx.x >> 1, half = blockIdx.x & 1;
  bf16x8 bfr[4];
#pragma unroll
  for (int kc = 0; kc < 4; ++kc)
    bfr[kc] = *(const bf16x8*)(vnbf + col * 256 + 128 + kc * 32 + quad * 8);
#pragma unroll
  for (int i = 0; i < 4; ++i) {
    int mt = half * 16 + wave * 4 + i;
    floatx4 acc;
#pragma unroll
    for (int r = 0; r < 4; ++r) acc[r] = 0.0f;
#pragma unroll
    for (int kc = 0; kc < 4; ++kc) {
      bf16x8 a = *(const bf16x8*)(dbf + ((size_t)(b * 512 + mt * 16 + col) << 7) +
                                  kc * 32 + quad * 8);
      acc = __builtin_amdgcn_mfma_f32_16x16x32_bf16(a, bfr[kc], acc, 0, 0, 0);
    }
#pragma unroll
    for (int r = 0; r < 4; ++r)
      ldb[((size_t)(b * 16 + col) << 9) + mt * 16 + quad * 4 + r] = acc[r];
  }
}

// ---------------------------------------------------------------------------
// lq rowdot (tiny, q-side only): out[(b*16+k)*32 + r] = Vn[k][0:128]·q[row]
// ---------------------------------------------------------------------------
__global__ __launch_bounds__(256) void gmn_rowdot16(const float* __restrict__ M, int rsh,
                                                    const float* __restrict__ Vn, int voff,
                                                    float* __restrict__ out) {
  __shared__ float sh_r[16 * 132];
  __shared__ float sh_v[16 * 132];
  int tid = threadIdx.x;
  int g0 = blockIdx.x * 16;
#pragma unroll
  for (int i = 0; i < 8; ++i) {
    int j = tid + 256 * i;
    int a = j >> 7, e = j & 127;
    sh_r[a * 132 + e] = M[(size_t)(g0 + a) * 128 + e];
    sh_v[a * 132 + e] = Vn[a * 256 + voff + e];
  }
  __syncthreads();
  int r = tid & 15, k = tid >> 4;
  float s = 0.0f;
#pragma unroll 8
  for (int e = 0; e < 128; ++e) s += sh_r[r * 132 + e] * sh_v[k * 132 + e];
  int g = g0 + r;
  int b = g >> rsh;
  int rr = g & ((1 << rsh) - 1);
  out[((b * 16 + k) << rsh) + rr] = s;
}

// ---------------------------------------------------------------------------
// rowwise softmax over 512 cols, in place. grid = rows, 256 threads.
// ---------------------------------------------------------------------------
__global__ __launch_bounds__(256) void gmn_softmax_rows(float* __restrict__ p) {
  __shared__ float sh[8];
  int tid = threadIdx.x;
  float* r = p + (size_t)blockIdx.x * 512;
  float v0 = r[tid], v1 = r[tid + 256];
  float m = fmaxf(v0, v1);
#pragma unroll
  for (int o = 32; o; o >>= 1) m = fmaxf(m, __shfl_xor(m, o, 64));
  if ((tid & 63) == 0) sh[tid >> 6] = m;
  __syncthreads();
  m = fmaxf(fmaxf(sh[0], sh[1]), fmaxf(sh[2], sh[3]));
  float e0 = expf(v0 - m), e1 = expf(v1 - m);
  float s = e0 + e1;
#pragma unroll
  for (int o = 32; o; o >>= 1) s += __shfl_xor(s, o, 64);
  if ((tid & 63) == 0) sh[4 + (tid >> 6)] = s;
  __syncthreads();
  s = sh[4] + sh[5] + sh[6] + sh[7];
  float inv = 1.0f / s;
  r[tid] = e0 * inv;
  r[tid + 256] = e1 * inv;
}

// ---------------------------------------------------------------------------
// MFMA NTN level kernel (unchanged core; adds fold_widx to skip combine pass)
// ---------------------------------------------------------------------------
__global__ __launch_bounds__(256) void gmn_level_mfma(
    const ushort* __restrict__ qw, const ushort* __restrict__ dbf,
    const float* __restrict__ att, const float* __restrict__ lqb,
    const float* __restrict__ ldb, const float* __restrict__ bn,
    const float* __restrict__ cw, const float* __restrict__ cb,
    const float* __restrict__ w_end, int o1, int o2, int do_facc, int fold_widx,
    float* __restrict__ Ebuf, float* __restrict__ accb) {
  int tid = threadIdx.x;
  int wave = tid >> 6, lane = tid & 63;
  int b = blockIdx.x >> 3, nc = blockIdx.x & 7;
  int col = lane & 15, quad = lane >> 4;
  int n = nc * 64 + wave * 16 + col;
  const ushort* dptr = dbf + (((size_t)(b * 512 + n)) << 7) + quad * 8;
  const ushort* qwb = qw + ((size_t)b << 16);
  floatx4 eacc[2], facc[2];
  float attv[2][4];
#pragma unroll
  for (int t = 0; t < 2; ++t) {
#pragma unroll
    for (int r = 0; r < 4; ++r) {
      eacc[t][r] = 0.0f;
      facc[t][r] = 0.0f;
      attv[t][r] = att[((b * 32 + t * 16 + quad * 4 + r) << 9) + n];
    }
  }
  float cbv = cb[0];
  for (int k = 0; k < 16; ++k) {
    floatx4 bil[2];
#pragma unroll
    for (int t = 0; t < 2; ++t)
#pragma unroll
      for (int r = 0; r < 4; ++r) bil[t][r] = 0.0f;
    const ushort* qk = qwb + (k << 12) + quad * 8;
#pragma unroll
    for (int kc = 0; kc < 4; ++kc) {
      bf16x8 bf = *(const bf16x8*)(dptr + kc * 32);
      bf16x8 a0 = *(const bf16x8*)(qk + (col << 7) + kc * 32);
      bf16x8 a1 = *(const bf16x8*)(qk + ((col + 16) << 7) + kc * 32);
      bil[0] = __builtin_amdgcn_mfma_f32_16x16x32_bf16(a0, bf, bil[0], 0, 0, 0);
      bil[1] = __builtin_amdgcn_mfma_f32_16x16x32_bf16(a1, bf, bil[1], 0, 0, 0);
    }
    float ldv = ldb[((b * 16 + k) << 9) + n];
    float bnk = bn[k], cwk = cw[k];
    float wkk = 0.0f;
    if (do_facc) {
      wkk = w_end[o1 + k];
      if (o2 >= 0) wkk += w_end[o2 + k];
    }
#pragma unroll
    for (int t = 0; t < 2; ++t) {
#pragma unroll
      for (int r = 0; r < 4; ++r) {
        float lqv = lqb[(b * 16 + k) * 32 + t * 16 + quad * 4 + r];
        float z = bil[t][r] + lqv + ldv + bnk;
        float he = attv[t][r] / (1.0f + expf(-z));
        eacc[t][r] = eacc[t][r] + cwk * he;
        facc[t][r] = facc[t][r] + wkk * he;
      }
    }
  }
  float wf = (fold_widx >= 0) ? w_end[fold_widx] : 0.0f;
#pragma unroll
  for (int t = 0; t < 2; ++t) {
#pragma unroll
    for (int r = 0; r < 4; ++r) {
      int idx = ((b * 32 + t * 16 + quad * 4 + r) << 9) + n;
      if (fold_widx >= 0) {
        accb[idx] += wf * (eacc[t][r] + cbv) + facc[t][r];
      } else {
        Ebuf[idx] = eacc[t][r] + cbv;
        if (do_facc) accb[idx] += facc[t][r];
      }
    }
  }
}

// acc += w_end[widx] * softmax(E_row)
__global__ __launch_bounds__(256) void gmn_combine(const float* __restrict__ Ebuf,
                                                   float* __restrict__ accb,
                                                   const float* __restrict__ w_end,
                                                   int widx) {
  __shared__ float sh[8];
  int tid = threadIdx.x;
  size_t base = (size_t)blockIdx.x * 512;
  float w = w_end[widx];
  float v0 = Ebuf[base + tid], v1 = Ebuf[base + tid + 256];
  float m = fmaxf(v0, v1);
#pragma unroll
  for (int o = 32; o; o >>= 1) m = fmaxf(m, __shfl_xor(m, o, 64));
  if ((tid & 63) == 0) sh[tid >> 6] = m;
  __syncthreads();
  m = fmaxf(fmaxf(sh[0], sh[1]), fmaxf(sh[2], sh[3]));
  float e0 = expf(v0 - m), e1 = expf(v1 - m);
  float s = e0 + e1;
#pragma unroll
  for (int o = 32; o; o >>= 1) s += __shfl_xor(s, o, 64);
  if ((tid & 63) == 0) sh[4 + (tid >> 6)] = s;
  __syncthreads();
  s = sh[4] + sh[5] + sh[6] + sh[7];
  float inv = 1.0f / s;
  accb[base + tid] += w * e0 * inv;
  accb[base + tid + 256] += w * e1 * inv;
}

// out = softmax(acc + b_end) rowwise
__global__ __launch_bounds__(256) void gmn_final(const float* __restrict__ accb,
                                                 const float* __restrict__ b_end,
                                                 float* __restrict__ out) {
  __shared__ float sh[8];
  int tid = threadIdx.x;
  size_t base = (size_t)blockIdx.x * 512;
  float be = b_end[0];
  float v0 = accb[base + tid] + be, v1 = accb[base + tid + 256] + be;
  float m = fmaxf(v0, v1);
#pragma unroll
  for (int o = 32; o; o >>= 1) m = fmaxf(m, __shfl_xor(m, o, 64));
  if ((tid & 63) == 0) sh[tid >> 6] = m;
  __syncthreads();
  m = fmaxf(fmaxf(sh[0], sh[1]), fmaxf(sh[2], sh[3]));
  float e0 = expf(v0 - m), e1 = expf(v1 - m);
  float s = e0 + e1;
#pragma unroll
  for (int o = 32; o; o >>= 1) s += __shfl_xor(s, o, 64);
  if ((tid & 63) == 0) sh[4 + (tid >> 6)] = s;
  __syncthreads();
  s = sh[4] + sh[5] + sh[6] + sh[7];
  float inv = 1.0f / s;
  out[base + tid] = e0 * inv;
  out[base + tid + 256] = e1 * inv;
}

// ---------------------------------------------------------------------------
// Host orchestration
// ---------------------------------------------------------------------------
extern "C" void kernel_launch(void* const* d_in, const int* in_sizes, int n_in,
                              void* d_out, int out_size, void* d_ws, size_t ws_size,
                              hipStream_t stream) {
  (void)in_sizes; (void)n_in; (void)out_size; (void)ws_size;
  const float* x_d = (const float*)d_in[0];
  const float* x_q = (const float*)d_in[1];
  const int* ei_d = (const int*)d_in[2];
  const int* ei_q = (const int*)d_in[3];
  const float* W1 = (const float*)d_in[6];
  const float* b1 = (const float*)d_in[7];
  const float* W2 = (const float*)d_in[8];
  const float* b2 = (const float*)d_in[9];
  const float* W3 = (const float*)d_in[10];
  const float* b3 = (const float*)d_in[11];
  const float* Wn[3] = {(const float*)d_in[12], (const float*)d_in[17], (const float*)d_in[22]};
  const float* Vn[3] = {(const float*)d_in[13], (const float*)d_in[18], (const float*)d_in[23]};
  const float* bn[3] = {(const float*)d_in[14], (const float*)d_in[19], (const float*)d_in[24]};
  const float* cw[3] = {(const float*)d_in[15], (const float*)d_in[20], (const float*)d_in[25]};
  const float* cb[3] = {(const float*)d_in[16], (const float*)d_in[21], (const float*)d_in[26]};
  const float* w_end = (const float*)d_in[27];
  const float* b_end = (const float*)d_in[28];
  float* out = (float*)d_out;

  char* wsp = (char*)d_ws;
  auto alloc = [&](size_t nbytes) {
    void* p = (void*)wsp;
    wsp += (nbytes + 255) & ~(size_t)255;
    return p;
  };
  float* dinv_d = (float*)alloc(cNd * 4);
  float* dinv_q = (float*)alloc(cNq * 4);
  int* cnt_d = (int*)alloc(cNd * 4);
  int* cnt_q = (int*)alloc(cNq * 4);
  int* rp_d = (int*)alloc(cNd * 4);
  int* rp_q = (int*)alloc(cNq * 4);
  int* cur_d = (int*)alloc(cNd * 4);
  int* cur_q = (int*)alloc(cNq * 4);
  int* col_d = (int*)alloc((size_t)cEd * 4);
  int* col_q = (int*)alloc((size_t)cEq * 4);
  int* bsum = (int*)alloc(64 * 4);
  ushort* xdbf = (ushort*)alloc((size_t)cNd * 64 * 2);
  ushort* xqbf = (ushort*)alloc((size_t)cNq * 64 * 2);
  ushort* w1T = (ushort*)alloc(128 * 64 * 2);
  ushort* w2T = (ushort*)alloc(128 * 128 * 2);
  ushort* w3T = (ushort*)alloc(128 * 128 * 2);
  ushort* wnT[3];
  for (int l = 0; l < 3; ++l) wnT[l] = (ushort*)alloc((size_t)16 * 128 * 128 * 2);
  ushort* vnbf[3];
  for (int l = 0; l < 3; ++l) vnbf[l] = (ushort*)alloc(16 * 256 * 2);
  ushort* htmp = (ushort*)alloc((size_t)cNd * 128 * 2);  // scaled bf16 staging
  ushort* dbf = (ushort*)alloc((size_t)cNd * 128 * 2);   // data activations bf16
  ushort* qbf[3];
  for (int l = 0; l < 3; ++l) qbf[l] = (ushort*)alloc((size_t)cNq * 128 * 2);
  float* qf[3];
  for (int l = 0; l < 3; ++l) qf[l] = (float*)alloc((size_t)cNq * 128 * 4);
  float* att = (float*)alloc((size_t)cB * cNQ * cND * 4);
  float* Ebuf = (float*)alloc((size_t)cB * cNQ * cND * 4);
  float* accb = (float*)alloc((size_t)cB * cNQ * cND * 4);
  float* lqb = (float*)alloc((size_t)cB * 16 * 32 * 4);
  float* ldb = (float*)alloc((size_t)cB * 16 * 512 * 4);
  ushort* qwbuf = (ushort*)alloc((size_t)cB * 16 * 32 * 128 * 2);

  const int* src_d = ei_d;
  const int* dst_d = ei_d + cEd;
  const int* src_q = ei_q;
  const int* dst_q = ei_q + cEq;

  hipMemsetAsync(cnt_d, 0, cNd * 4, stream);
  hipMemsetAsync(cnt_q, 0, cNq * 4, stream);
  hipMemsetAsync(cur_d, 0, cNd * 4, stream);
  hipMemsetAsync(cur_q, 0, cNq * 4, stream);
  hipMemsetAsync(accb, 0, (size_t)cB * cNQ * cND * 4, stream);

  // --- weight/input conversions (once) ---
  gmn_cvt<<<(cNd * 64 / 4 + 255) / 256, 256, 0, stream>>>(x_d, xdbf, cNd * 64 / 4);
  gmn_cvt<<<(cNq * 64 / 4 + 255) / 256, 256, 0, stream>>>(x_q, xqbf, cNq * 64 / 4);
  gmn_t2bf<<<1 * 2 * 4, 256, 0, stream>>>(W1, w1T, 64, 128);
  gmn_t2bf<<<1 * 4 * 4, 256, 0, stream>>>(W2, w2T, 128, 128);
  gmn_t2bf<<<1 * 4 * 4, 256, 0, stream>>>(W3, w3T, 128, 128);
  for (int l = 0; l < 3; ++l) {
    gmn_t2bf<<<16 * 4 * 4, 256, 0, stream>>>(Wn[l], wnT[l], 128, 128);
    gmn_cvt<<<(16 * 256 / 4 + 255) / 256, 256, 0, stream>>>(Vn[l], vnbf[l], 16 * 256 / 4);
  }

  // --- CSR + dinv ---
  gmn_count<<<cEd / 256, 256, 0, stream>>>(dst_d, cnt_d, cEd);
  gmn_count<<<cEq / 256, 256, 0, stream>>>(dst_q, cnt_q, cEq);
  gmn_scan_local<<<cNd / 1024, 1024, 0, stream>>>(cnt_d, rp_d, bsum);
  gmn_scan_off<<<1, 64, 0, stream>>>(bsum, cNd / 1024);
  gmn_scan_add<<<cNd / 1024, 1024, 0, stream>>>(rp_d, bsum);
  gmn_scan_local<<<cNq / 1024, 1024, 0, stream>>>(cnt_q, rp_q, bsum);
  gmn_scan_off<<<1, 64, 0, stream>>>(bsum, cNq / 1024);
  gmn_scan_add<<<cNq / 1024, 1024, 0, stream>>>(rp_q, bsum);
  gmn_dinv<<<cNd / 256, 256, 0, stream>>>(cnt_d, dinv_d, cNd);
  gmn_dinv<<<cNq / 256, 256, 0, stream>>>(cnt_q, dinv_q, cNq);
  gmn_fill<<<cEd / 256, 256, 0, stream>>>(src_d, dst_d, rp_d, cur_d, col_d, cEd);
  gmn_fill<<<cEq / 256, 256, 0, stream>>>(src_q, dst_q, rp_q, cur_q, col_q, cEq);

  // --- query GCN chain (q1,q2,q3) ---
  gmn_gemm_mfma<64><<<cNq / 64, 256, 0, stream>>>(xqbf, w1T, dinv_q, htmp);
  gmn_gather_bf<<<cNq / 8, 256, 0, stream>>>(htmp, rp_q, cnt_q, col_q, dinv_q, b1,
                                             qbf[0], qf[0], 1);
  gmn_gemm_mfma<128><<<cNq / 64, 256, 0, stream>>>(qbf[0], w2T, dinv_q, htmp);
  gmn_gather_bf<<<cNq / 8, 256, 0, stream>>>(htmp, rp_q, cnt_q, col_q, dinv_q, b2,
                                             qbf[1], qf[1], 1);
  gmn_gemm_mfma<128><<<cNq / 64, 256, 0, stream>>>(qbf[1], w3T, dinv_q, htmp);
  gmn_gather_bf<<<cNq / 8, 256, 0, stream>>>(htmp, rp_q, cnt_q, col_q, dinv_q, b3,
                                             qbf[2], qf[2], 1);

  const ushort* wT[3] = {w1T, w2T, w3T};
  const float* bias[3] = {b1, b2, b3};
  const int o1s[3] = {0, 19, 3};
  const int o2s[3] = {-1, -1, 35};
  const int dofac[3] = {0, 1, 1};
  const int foldw[3] = {-1, 1, -1};
  const int combw[3] = {0, -1, 2};

  for (int l = 0; l < 3; ++l) {
    // data GCN layer l -> dbf
    if (l == 0)
      gmn_gemm_mfma<64><<<cNd / 64, 256, 0, stream>>>(xdbf, w1T, dinv_d, htmp);
    else
      gmn_gemm_mfma<128><<<cNd / 64, 256, 0, stream>>>(dbf, wT[l], dinv_d, htmp);
    gmn_gather_bf<<<cNd / 8, 256, 0, stream>>>(htmp, rp_d, cnt_d, col_d, dinv_d, bias[l],
                                               dbf, (float*)nullptr, 0);
    // level l
    gmn_qw_mfma<<<cB * 16, 256, 0, stream>>>(qbf[l], wnT[l], qwbuf);
    gmn_rowdot16<<<cNq / 16, 256, 0, stream>>>(qf[l], 5, Vn[l], 0, lqb);
    gmn_ld_mfma<<<cB * 2, 256, 0, stream>>>(dbf, vnbf[l], ldb);
    gmn_logits_mfma<<<cB * 8, 256, 0, stream>>>(qbf[l], dbf, att);
    gmn_softmax_rows<<<cB * cNQ, 256, 0, stream>>>(att);
    gmn_level_mfma<<<cB * 8, 256, 0, stream>>>(qwbuf, dbf, att, lqb, ldb, bn[l], cw[l],
                                               cb[l], w_end, o1s[l], o2s[l], dofac[l],
                                               foldw[l], Ebuf, accb);
    if (combw[l] >= 0)
      gmn_combine<<<cB * cNQ, 256, 0, stream>>>(Ebuf, accb, w_end, combw[l]);
  }

  // --- final 1x1 conv bias + softmax over data nodes ---
  gmn_final<<<cB * cNQ, 256, 0, stream>>>(accb, b_end, out);
}

// Round 4
// 498.332 us; speedup vs baseline: 2.5315x; 1.0469x over previous
//
#include <hip/hip_runtime.h>
#include <math.h>

// ---------------------------------------------------------------------------
// Problem constants (fixed production sizes from the reference)
// ---------------------------------------------------------------------------
namespace {
constexpr int cB  = 64;
constexpr int cNQ = 32;
constexpr int cND = 512;
constexpr int cNd = cB * cND;   // 32768 data nodes
constexpr int cNq = cB * cNQ;   // 2048 query nodes
constexpr int cEd = cNd * 8;    // 262144 data edges
constexpr int cEq = cNq * 8;    // 16384 query edges
constexpr size_t cSZ = (size_t)cB * cNQ * cND;  // 1M elements per map
}

#define F4C(p) (*(const float4*)(p))
#define F4W(p) (*(float4*)(p))

typedef __attribute__((ext_vector_type(8))) __bf16 bf16x8;
typedef __attribute__((ext_vector_type(4))) float floatx4;

__device__ __forceinline__ ushort f2bf(float f) {
  union { float f; unsigned u; } v;
  v.f = f;
  unsigned u = v.u;
  unsigned r = (u + 0x7fffu + ((u >> 16) & 1u)) >> 16;
  return (ushort)r;
}
__device__ __forceinline__ float bf2f(ushort u) {
  union { unsigned u; float f; } v;
  v.u = ((unsigned)u) << 16;
  return v.f;
}
__device__ __forceinline__ float4 us4f4(ushort4 u) {
  return make_float4(bf2f(u.x), bf2f(u.y), bf2f(u.z), bf2f(u.w));
}
__device__ __forceinline__ ushort4 f4us4(float4 f) {
  ushort4 o;
  o.x = f2bf(f.x); o.y = f2bf(f.y); o.z = f2bf(f.z); o.w = f2bf(f.w);
  return o;
}

__device__ __forceinline__ float fexp2(float x) {
#if __has_builtin(__builtin_amdgcn_exp2f)
  return __builtin_amdgcn_exp2f(x);
#else
  return exp2f(x);
#endif
}
__device__ __forceinline__ float frcp(float x) {
#if __has_builtin(__builtin_amdgcn_rcpf)
  return __builtin_amdgcn_rcpf(x);
#else
  return 1.0f / x;
#endif
}
// sigmoid(z) = 1/(1+2^(-z*log2e))
__device__ __forceinline__ float fsigmoid(float z) {
  return frcp(1.0f + fexp2(z * -1.4426950408889634f));
}
__device__ __forceinline__ float fexp(float x) { return fexp2(x * 1.4426950408889634f); }

// ---------------------------------------------------------------------------
// Conversions
// ---------------------------------------------------------------------------
__global__ void gmn_cvt(const float* __restrict__ in, ushort* __restrict__ out, int N4) {
  int i = blockIdx.x * 256 + threadIdx.x;
  if (i < N4) *(ushort4*)(out + i * 4) = f4us4(F4C(in + (size_t)i * 4));
}

// out[bt][c][r] = bf16(in[bt][r][c]);  R,C multiples of 32
__global__ __launch_bounds__(256) void gmn_t2bf(const float* __restrict__ in,
                                                ushort* __restrict__ out, int R, int C) {
  __shared__ float tile[32][33];
  int tilesR = R >> 5, tilesC = C >> 5;
  int bt = blockIdx.x / (tilesR * tilesC);
  int rem = blockIdx.x - bt * tilesR * tilesC;
  int tr = rem / tilesC, tc = rem - tr * tilesC;
  int tx = threadIdx.x & 31, ty = threadIdx.x >> 5;
  const float* ib = in + (size_t)bt * R * C;
  ushort* ob = out + (size_t)bt * R * C;
#pragma unroll
  for (int i = 0; i < 4; ++i)
    tile[ty + i * 8][tx] = ib[(tr * 32 + ty + i * 8) * C + tc * 32 + tx];
  __syncthreads();
#pragma unroll
  for (int i = 0; i < 4; ++i)
    ob[(size_t)(tc * 32 + ty + i * 8) * R + tr * 32 + tx] = f2bf(tile[tx][ty + i * 8]);
}

// ---------------------------------------------------------------------------
// CSR construction
// ---------------------------------------------------------------------------
__global__ void gmn_count(const int* __restrict__ dst, int* __restrict__ cnt, int E) {
  int i = blockIdx.x * 256 + threadIdx.x;
  if (i < E) atomicAdd(&cnt[dst[i]], 1);
}

__global__ __launch_bounds__(1024) void gmn_scan_local(const int* __restrict__ cnt,
                                                       int* __restrict__ rp,
                                                       int* __restrict__ bsum) {
  __shared__ int sh[1024];
  int tid = threadIdx.x;
  int base = blockIdx.x * 1024;
  int v = cnt[base + tid];
  sh[tid] = v;
  __syncthreads();
  for (int off = 1; off < 1024; off <<= 1) {
    int t = (tid >= off) ? sh[tid - off] : 0;
    __syncthreads();
    sh[tid] += t;
    __syncthreads();
  }
  rp[base + tid] = sh[tid] - v;  // exclusive
  if (tid == 1023) bsum[blockIdx.x] = sh[1023];
}

__global__ void gmn_scan_off(int* __restrict__ bsum, int nb) {
  int l = threadIdx.x;  // 64 threads
  int v = (l < nb) ? bsum[l] : 0;
  int orig = v;
#pragma unroll
  for (int off = 1; off < 64; off <<= 1) {
    int t = __shfl_up(v, off, 64);
    if (l >= off) v += t;
  }
  if (l < nb) bsum[l] = v - orig;  // exclusive
}

__global__ __launch_bounds__(1024) void gmn_scan_add(int* __restrict__ rp,
                                                     const int* __restrict__ bsum) {
  rp[blockIdx.x * 1024 + threadIdx.x] += bsum[blockIdx.x];
}

__global__ void gmn_dinv(const int* __restrict__ cnt, float* __restrict__ dinv, int N) {
  int i = blockIdx.x * 256 + threadIdx.x;
  if (i < N) dinv[i] = 1.0f / sqrtf((float)(cnt[i] + 1));  // +1 self loop
}

__global__ void gmn_fill(const int* __restrict__ src, const int* __restrict__ dst,
                         const int* __restrict__ rp, int* __restrict__ cur,
                         int* __restrict__ col, int E) {
  int i = blockIdx.x * 256 + threadIdx.x;
  if (i < E) {
    int d = dst[i];
    int p = atomicAdd(&cur[d], 1);
    col[rp[d] + p] = src[i];
  }
}

// ---------------------------------------------------------------------------
// GCN dense: H[n][c] = bf16( dinv[n] * sum_d X[n][d] * W[d][c] )  via MFMA.
// ---------------------------------------------------------------------------
template <int KD>
__global__ __launch_bounds__(256) void gmn_gemm_mfma(const ushort* __restrict__ X,
                                                     const ushort* __restrict__ WT,
                                                     const float* __restrict__ dinv,
                                                     ushort* __restrict__ H) {
  int tid = threadIdx.x;
  int wave = tid >> 6, lane = tid & 63;
  int col = lane & 15, quad = lane >> 4;
  int m0 = blockIdx.x * 64 + wave * 16;
  floatx4 acc[8];
#pragma unroll
  for (int ct = 0; ct < 8; ++ct)
#pragma unroll
    for (int r = 0; r < 4; ++r) acc[ct][r] = 0.0f;
#pragma unroll
  for (int kc = 0; kc < KD / 32; ++kc) {
    bf16x8 a = *(const bf16x8*)(X + (size_t)(m0 + col) * KD + kc * 32 + quad * 8);
#pragma unroll
    for (int ct = 0; ct < 8; ++ct) {
      bf16x8 b = *(const bf16x8*)(WT + (size_t)(ct * 16 + col) * KD + kc * 32 + quad * 8);
      acc[ct] = __builtin_amdgcn_mfma_f32_16x16x32_bf16(a, b, acc[ct], 0, 0, 0);
    }
  }
  float sc[4];
#pragma unroll
  for (int r = 0; r < 4; ++r) sc[r] = dinv[m0 + quad * 4 + r];
#pragma unroll
  for (int ct = 0; ct < 8; ++ct)
#pragma unroll
    for (int r = 0; r < 4; ++r)
      H[(size_t)(m0 + quad * 4 + r) * 128 + ct * 16 + col] = f2bf(acc[ct][r] * sc[r]);
}

// ---------------------------------------------------------------------------
// GCN aggregate from pre-scaled bf16 rows.
// ---------------------------------------------------------------------------
__global__ __launch_bounds__(256) void gmn_gather_bf(
    const ushort* __restrict__ hs, const int* __restrict__ rp,
    const int* __restrict__ cnt, const int* __restrict__ col,
    const float* __restrict__ dinv, const float* __restrict__ bias,
    ushort* __restrict__ outbf, float* __restrict__ outf, int do_f) {
  int tid = threadIdx.x;
  int node = blockIdx.x * 8 + (tid >> 5);
  int l = tid & 31;
  int c = cnt[node], s0 = rp[node];
  float dt = dinv[node];
  float4 acc = us4f4(*(const ushort4*)(hs + (size_t)node * 128 + l * 4));
  int cm = c < 32 ? c : 32;
  for (int j0 = 0; j0 < cm; j0 += 8) {
    int ss[8];
    ushort4 v[8];
#pragma unroll
    for (int t = 0; t < 8; ++t) {
      int jj = j0 + t;
      ss[t] = col[s0 + (jj < c ? jj : c - 1)];
    }
#pragma unroll
    for (int t = 0; t < 8; ++t)
      v[t] = *(const ushort4*)(hs + (size_t)ss[t] * 128 + l * 4);
#pragma unroll
    for (int t = 0; t < 8; ++t) {
      if (j0 + t < cm) {
        float4 f = us4f4(v[t]);
        acc.x += f.x; acc.y += f.y; acc.z += f.z; acc.w += f.w;
      }
    }
  }
  for (int j = 32; j < c; ++j) {
    int s = col[s0 + j];
    float4 f = us4f4(*(const ushort4*)(hs + (size_t)s * 128 + l * 4));
    acc.x += f.x; acc.y += f.y; acc.z += f.z; acc.w += f.w;
  }
  float4 bv = F4C(bias + l * 4);
  float4 r;
  r.x = fmaxf(acc.x * dt + bv.x, 0.0f);
  r.y = fmaxf(acc.y * dt + bv.y, 0.0f);
  r.z = fmaxf(acc.z * dt + bv.z, 0.0f);
  r.w = fmaxf(acc.w * dt + bv.w, 0.0f);
  *(ushort4*)(outbf + (size_t)node * 128 + l * 4) = f4us4(r);
  if (do_f) F4W(outf + (size_t)node * 128 + l * 4) = r;
}

// ---------------------------------------------------------------------------
// qW[b,k] = q[b] @ Wn[k]  (bf16 MFMA, bf16 out). grid B*16, 4 waves.
// ---------------------------------------------------------------------------
__global__ __launch_bounds__(256) void gmn_qw_mfma(const ushort* __restrict__ qbf,
                                                   const ushort* __restrict__ wnT,
                                                   ushort* __restrict__ qw) {
  int tid = threadIdx.x;
  int wave = tid >> 6, lane = tid & 63;
  int col = lane & 15, quad = lane >> 4;
  int b = blockIdx.x >> 4, k = blockIdx.x & 15;
  int et0 = wave * 2;
  floatx4 acc[2][2];
#pragma unroll
  for (int qt = 0; qt < 2; ++qt)
#pragma unroll
    for (int ei = 0; ei < 2; ++ei)
#pragma unroll
      for (int r = 0; r < 4; ++r) acc[qt][ei][r] = 0.0f;
#pragma unroll
  for (int kc = 0; kc < 4; ++kc) {
    bf16x8 a0 = *(const bf16x8*)(qbf + (size_t)(b * 32 + col) * 128 + kc * 32 + quad * 8);
    bf16x8 a1 = *(const bf16x8*)(qbf + (size_t)(b * 32 + 16 + col) * 128 + kc * 32 + quad * 8);
#pragma unroll
    for (int ei = 0; ei < 2; ++ei) {
      bf16x8 bf = *(const bf16x8*)(wnT + (size_t)(k * 128 + (et0 + ei) * 16 + col) * 128 +
                                   kc * 32 + quad * 8);
      acc[0][ei] = __builtin_amdgcn_mfma_f32_16x16x32_bf16(a0, bf, acc[0][ei], 0, 0, 0);
      acc[1][ei] = __builtin_amdgcn_mfma_f32_16x16x32_bf16(a1, bf, acc[1][ei], 0, 0, 0);
    }
  }
#pragma unroll
  for (int qt = 0; qt < 2; ++qt)
#pragma unroll
    for (int ei = 0; ei < 2; ++ei)
#pragma unroll
      for (int r = 0; r < 4; ++r)
        qw[((size_t)(b * 16 + k) << 12) + (qt * 16 + quad * 4 + r) * 128 +
           (et0 + ei) * 16 + col] = f2bf(acc[qt][ei][r]);
}

// ---------------------------------------------------------------------------
// attention logits via MFMA: att[b,q,n] = (q·d)/sqrt(128). grid B*8, 4 waves.
// ---------------------------------------------------------------------------
__global__ __launch_bounds__(256) void gmn_logits_mfma(const ushort* __restrict__ qbf,
                                                       const ushort* __restrict__ dbf,
                                                       float* __restrict__ att) {
  int tid = threadIdx.x;
  int wave = tid >> 6, lane = tid & 63;
  int col = lane & 15, quad = lane >> 4;
  int b = blockIdx.x >> 3, nc = blockIdx.x & 7;
  int n = nc * 64 + wave * 16 + col;
  floatx4 acc[2];
#pragma unroll
  for (int qt = 0; qt < 2; ++qt)
#pragma unroll
    for (int r = 0; r < 4; ++r) acc[qt][r] = 0.0f;
#pragma unroll
  for (int kc = 0; kc < 4; ++kc) {
    bf16x8 bf = *(const bf16x8*)(dbf + ((size_t)(b * 512 + n) << 7) + kc * 32 + quad * 8);
    bf16x8 a0 = *(const bf16x8*)(qbf + (size_t)(b * 32 + col) * 128 + kc * 32 + quad * 8);
    bf16x8 a1 = *(const bf16x8*)(qbf + (size_t)(b * 32 + 16 + col) * 128 + kc * 32 + quad * 8);
    acc[0] = __builtin_amdgcn_mfma_f32_16x16x32_bf16(a0, bf, acc[0], 0, 0, 0);
    acc[1] = __builtin_amdgcn_mfma_f32_16x16x32_bf16(a1, bf, acc[1], 0, 0, 0);
  }
  const float sc = 1.0f / sqrtf(128.0f);
#pragma unroll
  for (int qt = 0; qt < 2; ++qt)
#pragma unroll
    for (int r = 0; r < 4; ++r)
      att[((size_t)(b * 32 + qt * 16 + quad * 4 + r) << 9) + n] = acc[qt][r] * sc;
}

// ---------------------------------------------------------------------------
// ld[b,k,n] = sum_d dbf[b,n,d] * Vn[k][128+d]  via MFMA. grid cB*2, 4 waves.
// ---------------------------------------------------------------------------
__global__ __launch_bounds__(256) void gmn_ld_mfma(const ushort* __restrict__ dbf,
                                                   const ushort* __restrict__ vnbf,
                                                   float* __restrict__ ldb) {
  int tid = threadIdx.x;
  int wave = tid >> 6, lane = tid & 63;
  int col = lane & 15, quad = lane >> 4;
  int b = blockIdx.x >> 1, half = blockIdx.x & 1;
  bf16x8 bfr[4];
#pragma unroll
  for (int kc = 0; kc < 4; ++kc)
    bfr[kc] = *(const bf16x8*)(vnbf + col * 256 + 128 + kc * 32 + quad * 8);
#pragma unroll
  for (int i = 0; i < 4; ++i) {
    int mt = half * 16 + wave * 4 + i;
    floatx4 acc;
#pragma unroll
    for (int r = 0; r < 4; ++r) acc[r] = 0.0f;
#pragma unroll
    for (int kc = 0; kc < 4; ++kc) {
      bf16x8 a = *(const bf16x8*)(dbf + ((size_t)(b * 512 + mt * 16 + col) << 7) +
                                  kc * 32 + quad * 8);
      acc = __builtin_amdgcn_mfma_f32_16x16x32_bf16(a, bfr[kc], acc, 0, 0, 0);
    }
#pragma unroll
    for (int r = 0; r < 4; ++r)
      ldb[((size_t)(b * 16 + col) << 9) + mt * 16 + quad * 4 + r] = acc[r];
  }
}

// ---------------------------------------------------------------------------
// lq rowdot (tiny, q-side only)
// ---------------------------------------------------------------------------
__global__ __launch_bounds__(256) void gmn_rowdot16(const float* __restrict__ M, int rsh,
                                                    const float* __restrict__ Vn, int voff,
                                                    float* __restrict__ out) {
  __shared__ float sh_r[16 * 132];
  __shared__ float sh_v[16 * 132];
  int tid = threadIdx.x;
  int g0 = blockIdx.x * 16;
#pragma unroll
  for (int i = 0; i < 8; ++i) {
    int j = tid + 256 * i;
    int a = j >> 7, e = j & 127;
    sh_r[a * 132 + e] = M[(size_t)(g0 + a) * 128 + e];
    sh_v[a * 132 + e] = Vn[a * 256 + voff + e];
  }
  __syncthreads();
  int r = tid & 15, k = tid >> 4;
  float s = 0.0f;
#pragma unroll 8
  for (int e = 0; e < 128; ++e) s += sh_r[r * 132 + e] * sh_v[k * 132 + e];
  int g = g0 + r;
  int b = g >> rsh;
  int rr = g & ((1 << rsh) - 1);
  out[((b * 16 + k) << rsh) + rr] = s;
}

// ---------------------------------------------------------------------------
// rowwise softmax over 512 cols, in place. grid = rows, 256 threads.
// ---------------------------------------------------------------------------
__global__ __launch_bounds__(256) void gmn_softmax_rows(float* __restrict__ p) {
  __shared__ float sh[8];
  int tid = threadIdx.x;
  float* r = p + (size_t)blockIdx.x * 512;
  float v0 = r[tid], v1 = r[tid + 256];
  float m = fmaxf(v0, v1);
#pragma unroll
  for (int o = 32; o; o >>= 1) m = fmaxf(m, __shfl_xor(m, o, 64));
  if ((tid & 63) == 0) sh[tid >> 6] = m;
  __syncthreads();
  m = fmaxf(fmaxf(sh[0], sh[1]), fmaxf(sh[2], sh[3]));
  float e0 = fexp(v0 - m), e1 = fexp(v1 - m);
  float s = e0 + e1;
#pragma unroll
  for (int o = 32; o; o >>= 1) s += __shfl_xor(s, o, 64);
  if ((tid & 63) == 0) sh[4 + (tid >> 6)] = s;
  __syncthreads();
  s = sh[4] + sh[5] + sh[6] + sh[7];
  float inv = frcp(s);
  r[tid] = e0 * inv;
  r[tid + 256] = e1 * inv;
}

// ---------------------------------------------------------------------------
// MFMA NTN level kernel, split-k x2. grid = B*8*2, 256 thr = 4 waves.
// blockIdx = ((b*8+nc)<<1)|kh, kh owns k in [kh*8, kh*8+8).
// att factored out (applied in combine2). Writes sigmoid-sum partials:
//   Epart[kh][b,q,n] = sum_k cw_k * sig(z_k)
//   Fpart[kh][b,q,n] = sum_k wk_k * sig(z_k)   (if do_facc)
// ---------------------------------------------------------------------------
__global__ __launch_bounds__(256, 4) void gmn_level_mfma(
    const ushort* __restrict__ qw, const ushort* __restrict__ dbf,
    const float* __restrict__ lqb, const float* __restrict__ ldb,
    const float* __restrict__ bn, const float* __restrict__ cw,
    const float* __restrict__ w_end, int o1, int o2, int do_facc,
    float* __restrict__ Ebuf, float* __restrict__ Fbuf) {
  __shared__ float s_ld[8 * 64];
  __shared__ float s_lq[8 * 32];
  int tid = threadIdx.x;
  int wave = tid >> 6, lane = tid & 63;
  int kh = blockIdx.x & 1;
  int rest = blockIdx.x >> 1;
  int b = rest >> 3, nc = rest & 7;
  int k0 = kh * 8;
  int col = lane & 15, quad = lane >> 4;
  int nn = wave * 16 + col;
  int n = nc * 64 + nn;

  // stage ldb/lqb chunks
#pragma unroll
  for (int i = 0; i < 2; ++i) {
    int j = tid + 256 * i;
    int kk = j >> 6, nl = j & 63;
    s_ld[j] = ldb[((b * 16 + k0 + kk) << 9) + nc * 64 + nl];
  }
  {
    int kk = tid >> 5, qq = tid & 31;
    s_lq[tid] = lqb[(b * 16 + k0 + kk) * 32 + qq];
  }
  __syncthreads();

  // per-k uniform scalars
  float bnk[8], cwk[8], wkk[8];
#pragma unroll
  for (int kk = 0; kk < 8; ++kk) {
    bnk[kk] = bn[k0 + kk];
    cwk[kk] = cw[k0 + kk];
    float w = 0.0f;
    if (do_facc) {
      w = w_end[o1 + k0 + kk];
      if (o2 >= 0) w += w_end[o2 + k0 + kk];
    }
    wkk[kk] = w;
  }

  // k-invariant dbf fragments (B operand)
  const ushort* dptr = dbf + (((size_t)(b * 512 + n)) << 7) + quad * 8;
  bf16x8 bfr[4];
#pragma unroll
  for (int kc = 0; kc < 4; ++kc) bfr[kc] = *(const bf16x8*)(dptr + kc * 32);

  const ushort* qwb = qw + ((size_t)b << 16) + (k0 << 12) + quad * 8;
  floatx4 eacc[2], facc[2];
#pragma unroll
  for (int t = 0; t < 2; ++t)
#pragma unroll
    for (int r = 0; r < 4; ++r) { eacc[t][r] = 0.0f; facc[t][r] = 0.0f; }

#pragma unroll 2
  for (int kk = 0; kk < 8; ++kk) {
    const ushort* qk = qwb + (kk << 12);
    floatx4 bil[2];
#pragma unroll
    for (int t = 0; t < 2; ++t)
#pragma unroll
      for (int r = 0; r < 4; ++r) bil[t][r] = 0.0f;
#pragma unroll
    for (int kc = 0; kc < 4; ++kc) {
      bf16x8 a0 = *(const bf16x8*)(qk + (col << 7) + kc * 32);
      bf16x8 a1 = *(const bf16x8*)(qk + ((col + 16) << 7) + kc * 32);
      bil[0] = __builtin_amdgcn_mfma_f32_16x16x32_bf16(a0, bfr[kc], bil[0], 0, 0, 0);
      bil[1] = __builtin_amdgcn_mfma_f32_16x16x32_bf16(a1, bfr[kc], bil[1], 0, 0, 0);
    }
    float ldv = s_ld[kk * 64 + nn] + bnk[kk];
#pragma unroll
    for (int t = 0; t < 2; ++t) {
#pragma unroll
      for (int r = 0; r < 4; ++r) {
        float lqv = s_lq[kk * 32 + t * 16 + quad * 4 + r];
        float sg = fsigmoid(bil[t][r] + lqv + ldv);
        eacc[t][r] += cwk[kk] * sg;
        facc[t][r] += wkk[kk] * sg;
      }
    }
  }

  float* Ep = Ebuf + (size_t)kh * cSZ;
  float* Fp = Fbuf + (size_t)kh * cSZ;
#pragma unroll
  for (int t = 0; t < 2; ++t) {
#pragma unroll
    for (int r = 0; r < 4; ++r) {
      size_t idx = ((size_t)(b * 32 + t * 16 + quad * 4 + r) << 9) + n;
      Ep[idx] = eacc[t][r];
      if (do_facc) Fp[idx] = facc[t][r];
    }
  }
}

// ---------------------------------------------------------------------------
// combine partials: v = att*(E0+E1); f = att*(F0+F1)
// accb (+)= w*(do_sm ? softmax_row(v) : v) + f.  grid = rows (2048).
// ---------------------------------------------------------------------------
__global__ __launch_bounds__(256) void gmn_combine2(
    const float* __restrict__ Ebuf, const float* __restrict__ Fbuf,
    const float* __restrict__ att, float* __restrict__ accb,
    const float* __restrict__ w_end, int widx, int do_sm, int hasF, int do_init) {
  __shared__ float sh[8];
  int tid = threadIdx.x;
  size_t base = (size_t)blockIdx.x * 512;
  size_t i0 = base + tid, i1 = base + tid + 256;
  float w = w_end[widx];
  float a0 = att[i0], a1 = att[i1];
  float v0 = a0 * (Ebuf[i0] + Ebuf[i0 + cSZ]);
  float v1 = a1 * (Ebuf[i1] + Ebuf[i1 + cSZ]);
  float f0 = 0.0f, f1 = 0.0f;
  if (hasF) {
    f0 = a0 * (Fbuf[i0] + Fbuf[i0 + cSZ]);
    f1 = a1 * (Fbuf[i1] + Fbuf[i1 + cSZ]);
  }
  if (do_sm) {
    float m = fmaxf(v0, v1);
#pragma unroll
    for (int o = 32; o; o >>= 1) m = fmaxf(m, __shfl_xor(m, o, 64));
    if ((tid & 63) == 0) sh[tid >> 6] = m;
    __syncthreads();
    m = fmaxf(fmaxf(sh[0], sh[1]), fmaxf(sh[2], sh[3]));
    float e0 = fexp(v0 - m), e1 = fexp(v1 - m);
    float s = e0 + e1;
#pragma unroll
    for (int o = 32; o; o >>= 1) s += __shfl_xor(s, o, 64);
    if ((tid & 63) == 0) sh[4 + (tid >> 6)] = s;
    __syncthreads();
    s = sh[4] + sh[5] + sh[6] + sh[7];
    float inv = frcp(s);
    v0 = e0 * inv;
    v1 = e1 * inv;
  }
  float t0 = w * v0 + f0, t1 = w * v1 + f1;
  if (do_init) {
    accb[i0] = t0;
    accb[i1] = t1;
  } else {
    accb[i0] += t0;
    accb[i1] += t1;
  }
}

// out = softmax(acc + b_end) rowwise
__global__ __launch_bounds__(256) void gmn_final(const float* __restrict__ accb,
                                                 const float* __restrict__ b_end,
                                                 float* __restrict__ out) {
  __shared__ float sh[8];
  int tid = threadIdx.x;
  size_t base = (size_t)blockIdx.x * 512;
  float be = b_end[0];
  float v0 = accb[base + tid] + be, v1 = accb[base + tid + 256] + be;
  float m = fmaxf(v0, v1);
#pragma unroll
  for (int o = 32; o; o >>= 1) m = fmaxf(m, __shfl_xor(m, o, 64));
  if ((tid & 63) == 0) sh[tid >> 6] = m;
  __syncthreads();
  m = fmaxf(fmaxf(sh[0], sh[1]), fmaxf(sh[2], sh[3]));
  float e0 = fexp(v0 - m), e1 = fexp(v1 - m);
  float s = e0 + e1;
#pragma unroll
  for (int o = 32; o; o >>= 1) s += __shfl_xor(s, o, 64);
  if ((tid & 63) == 0) sh[4 + (tid >> 6)] = s;
  __syncthreads();
  s = sh[4] + sh[5] + sh[6] + sh[7];
  float inv = frcp(s);
  out[base + tid] = e0 * inv;
  out[base + tid + 256] = e1 * inv;
}

// ---------------------------------------------------------------------------
// Host orchestration
// ---------------------------------------------------------------------------
extern "C" void kernel_launch(void* const* d_in, const int* in_sizes, int n_in,
                              void* d_out, int out_size, void* d_ws, size_t ws_size,
                              hipStream_t stream) {
  (void)in_sizes; (void)n_in; (void)out_size; (void)ws_size;
  const float* x_d = (const float*)d_in[0];
  const float* x_q = (const float*)d_in[1];
  const int* ei_d = (const int*)d_in[2];
  const int* ei_q = (const int*)d_in[3];
  const float* W1 = (const float*)d_in[6];
  const float* b1 = (const float*)d_in[7];
  const float* W2 = (const float*)d_in[8];
  const float* b2 = (const float*)d_in[9];
  const float* W3 = (const float*)d_in[10];
  const float* b3 = (const float*)d_in[11];
  const float* Wn[3] = {(const float*)d_in[12], (const float*)d_in[17], (const float*)d_in[22]};
  const float* Vn[3] = {(const float*)d_in[13], (const float*)d_in[18], (const float*)d_in[23]};
  const float* bn[3] = {(const float*)d_in[14], (const float*)d_in[19], (const float*)d_in[24]};
  const float* cw[3] = {(const float*)d_in[15], (const float*)d_in[20], (const float*)d_in[25]};
  const float* w_end = (const float*)d_in[27];
  const float* b_end = (const float*)d_in[28];
  float* out = (float*)d_out;

  char* wsp = (char*)d_ws;
  auto alloc = [&](size_t nbytes) {
    void* p = (void*)wsp;
    wsp += (nbytes + 255) & ~(size_t)255;
    return p;
  };
  float* dinv_d = (float*)alloc(cNd * 4);
  float* dinv_q = (float*)alloc(cNq * 4);
  int* cnt_d = (int*)alloc(cNd * 4);
  int* cnt_q = (int*)alloc(cNq * 4);
  int* rp_d = (int*)alloc(cNd * 4);
  int* rp_q = (int*)alloc(cNq * 4);
  int* cur_d = (int*)alloc(cNd * 4);
  int* cur_q = (int*)alloc(cNq * 4);
  int* col_d = (int*)alloc((size_t)cEd * 4);
  int* col_q = (int*)alloc((size_t)cEq * 4);
  int* bsum = (int*)alloc(64 * 4);
  ushort* xdbf = (ushort*)alloc((size_t)cNd * 64 * 2);
  ushort* xqbf = (ushort*)alloc((size_t)cNq * 64 * 2);
  ushort* w1T = (ushort*)alloc(128 * 64 * 2);
  ushort* w2T = (ushort*)alloc(128 * 128 * 2);
  ushort* w3T = (ushort*)alloc(128 * 128 * 2);
  ushort* wnT[3];
  for (int l = 0; l < 3; ++l) wnT[l] = (ushort*)alloc((size_t)16 * 128 * 128 * 2);
  ushort* vnbf[3];
  for (int l = 0; l < 3; ++l) vnbf[l] = (ushort*)alloc(16 * 256 * 2);
  ushort* htmp = (ushort*)alloc((size_t)cNd * 128 * 2);
  ushort* dbf = (ushort*)alloc((size_t)cNd * 128 * 2);
  ushort* qbf[3];
  for (int l = 0; l < 3; ++l) qbf[l] = (ushort*)alloc((size_t)cNq * 128 * 2);
  float* qf[3];
  for (int l = 0; l < 3; ++l) qf[l] = (float*)alloc((size_t)cNq * 128 * 4);
  float* att = (float*)alloc(cSZ * 4);
  float* Ebuf = (float*)alloc(cSZ * 2 * 4);  // 2 k-split partials
  float* Fbuf = (float*)alloc(cSZ * 2 * 4);
  float* accb = (float*)alloc(cSZ * 4);
  float* lqb = (float*)alloc((size_t)cB * 16 * 32 * 4);
  float* ldb = (float*)alloc((size_t)cB * 16 * 512 * 4);
  ushort* qwbuf = (ushort*)alloc((size_t)cB * 16 * 32 * 128 * 2);

  const int* src_d = ei_d;
  const int* dst_d = ei_d + cEd;
  const int* src_q = ei_q;
  const int* dst_q = ei_q + cEq;

  hipMemsetAsync(cnt_d, 0, cNd * 4, stream);
  hipMemsetAsync(cnt_q, 0, cNq * 4, stream);
  hipMemsetAsync(cur_d, 0, cNd * 4, stream);
  hipMemsetAsync(cur_q, 0, cNq * 4, stream);

  // --- weight/input conversions (once) ---
  gmn_cvt<<<(cNd * 64 / 4 + 255) / 256, 256, 0, stream>>>(x_d, xdbf, cNd * 64 / 4);
  gmn_cvt<<<(cNq * 64 / 4 + 255) / 256, 256, 0, stream>>>(x_q, xqbf, cNq * 64 / 4);
  gmn_t2bf<<<1 * 2 * 4, 256, 0, stream>>>(W1, w1T, 64, 128);
  gmn_t2bf<<<1 * 4 * 4, 256, 0, stream>>>(W2, w2T, 128, 128);
  gmn_t2bf<<<1 * 4 * 4, 256, 0, stream>>>(W3, w3T, 128, 128);
  for (int l = 0; l < 3; ++l) {
    gmn_t2bf<<<16 * 4 * 4, 256, 0, stream>>>(Wn[l], wnT[l], 128, 128);
    gmn_cvt<<<(16 * 256 / 4 + 255) / 256, 256, 0, stream>>>(Vn[l], vnbf[l], 16 * 256 / 4);
  }

  // --- CSR + dinv ---
  gmn_count<<<cEd / 256, 256, 0, stream>>>(dst_d, cnt_d, cEd);
  gmn_count<<<cEq / 256, 256, 0, stream>>>(dst_q, cnt_q, cEq);
  gmn_scan_local<<<cNd / 1024, 1024, 0, stream>>>(cnt_d, rp_d, bsum);
  gmn_scan_off<<<1, 64, 0, stream>>>(bsum, cNd / 1024);
  gmn_scan_add<<<cNd / 1024, 1024, 0, stream>>>(rp_d, bsum);
  gmn_scan_local<<<cNq / 1024, 1024, 0, stream>>>(cnt_q, rp_q, bsum);
  gmn_scan_off<<<1, 64, 0, stream>>>(bsum, cNq / 1024);
  gmn_scan_add<<<cNq / 1024, 1024, 0, stream>>>(rp_q, bsum);
  gmn_dinv<<<cNd / 256, 256, 0, stream>>>(cnt_d, dinv_d, cNd);
  gmn_dinv<<<cNq / 256, 256, 0, stream>>>(cnt_q, dinv_q, cNq);
  gmn_fill<<<cEd / 256, 256, 0, stream>>>(src_d, dst_d, rp_d, cur_d, col_d, cEd);
  gmn_fill<<<cEq / 256, 256, 0, stream>>>(src_q, dst_q, rp_q, cur_q, col_q, cEq);

  // --- query GCN chain (q1,q2,q3) ---
  gmn_gemm_mfma<64><<<cNq / 64, 256, 0, stream>>>(xqbf, w1T, dinv_q, htmp);
  gmn_gather_bf<<<cNq / 8, 256, 0, stream>>>(htmp, rp_q, cnt_q, col_q, dinv_q, b1,
                                             qbf[0], qf[0], 1);
  gmn_gemm_mfma<128><<<cNq / 64, 256, 0, stream>>>(qbf[0], w2T, dinv_q, htmp);
  gmn_gather_bf<<<cNq / 8, 256, 0, stream>>>(htmp, rp_q, cnt_q, col_q, dinv_q, b2,
                                             qbf[1], qf[1], 1);
  gmn_gemm_mfma<128><<<cNq / 64, 256, 0, stream>>>(qbf[1], w3T, dinv_q, htmp);
  gmn_gather_bf<<<cNq / 8, 256, 0, stream>>>(htmp, rp_q, cnt_q, col_q, dinv_q, b3,
                                             qbf[2], qf[2], 1);

  const ushort* wT[3] = {w1T, w2T, w3T};
  const float* bias[3] = {b1, b2, b3};
  const int o1s[3] = {0, 19, 3};
  const int o2s[3] = {-1, -1, 35};
  const int dofac[3] = {0, 1, 1};
  const int widxs[3] = {0, 1, 2};
  const int dosms[3] = {1, 0, 1};

  for (int l = 0; l < 3; ++l) {
    // data GCN layer l -> dbf
    if (l == 0)
      gmn_gemm_mfma<64><<<cNd / 64, 256, 0, stream>>>(xdbf, w1T, dinv_d, htmp);
    else
      gmn_gemm_mfma<128><<<cNd / 64, 256, 0, stream>>>(dbf, wT[l], dinv_d, htmp);
    gmn_gather_bf<<<cNd / 8, 256, 0, stream>>>(htmp, rp_d, cnt_d, col_d, dinv_d, bias[l],
                                               dbf, (float*)nullptr, 0);
    // level l
    gmn_qw_mfma<<<cB * 16, 256, 0, stream>>>(qbf[l], wnT[l], qwbuf);
    gmn_rowdot16<<<cNq / 16, 256, 0, stream>>>(qf[l], 5, Vn[l], 0, lqb);
    gmn_ld_mfma<<<cB * 2, 256, 0, stream>>>(dbf, vnbf[l], ldb);
    gmn_logits_mfma<<<cB * 8, 256, 0, stream>>>(qbf[l], dbf, att);
    gmn_softmax_rows<<<cB * cNQ, 256, 0, stream>>>(att);
    gmn_level_mfma<<<cB * 8 * 2, 256, 0, stream>>>(qwbuf, dbf, lqb, ldb, bn[l], cw[l],
                                                   w_end, o1s[l], o2s[l], dofac[l],
                                                   Ebuf, Fbuf);
    gmn_combine2<<<cB * cNQ, 256, 0, stream>>>(Ebuf, Fbuf, att, accb, w_end, widxs[l],
                                               dosms[l], dofac[l], l == 0 ? 1 : 0);
  }

  // --- final 1x1 conv bias + softmax over data nodes ---
  gmn_final<<<cB * cNQ, 256, 0, stream>>>(accb, b_end, out);
}

// Round 5
// 406.414 us; speedup vs baseline: 3.1040x; 1.2262x over previous
//
#include <hip/hip_runtime.h>
#include <math.h>

// ---------------------------------------------------------------------------
// Problem constants (fixed production sizes from the reference)
// ---------------------------------------------------------------------------
namespace {
constexpr int cB  = 64;
constexpr int cNQ = 32;
constexpr int cND = 512;
constexpr int cNd = cB * cND;   // 32768 data nodes
constexpr int cNq = cB * cNQ;   // 2048 query nodes
constexpr int cEd = cNd * 8;    // 262144 data edges
constexpr int cEq = cNq * 8;    // 16384 query edges
constexpr size_t cSZ = (size_t)cB * cNQ * cND;  // 1M elements per map
}

#define F4C(p) (*(const float4*)(p))
#define F4W(p) (*(float4*)(p))

typedef __attribute__((ext_vector_type(8))) __bf16 bf16x8;
typedef __attribute__((ext_vector_type(4))) float floatx4;

__device__ __forceinline__ ushort f2bf(float f) {
  union { float f; unsigned u; } v;
  v.f = f;
  unsigned u = v.u;
  unsigned r = (u + 0x7fffu + ((u >> 16) & 1u)) >> 16;
  return (ushort)r;
}
__device__ __forceinline__ float bf2f(ushort u) {
  union { unsigned u; float f; } v;
  v.u = ((unsigned)u) << 16;
  return v.f;
}
__device__ __forceinline__ float4 us4f4(ushort4 u) {
  return make_float4(bf2f(u.x), bf2f(u.y), bf2f(u.z), bf2f(u.w));
}
__device__ __forceinline__ ushort4 f4us4(float4 f) {
  ushort4 o;
  o.x = f2bf(f.x); o.y = f2bf(f.y); o.z = f2bf(f.z); o.w = f2bf(f.w);
  return o;
}

__device__ __forceinline__ float fexp2(float x) {
#if __has_builtin(__builtin_amdgcn_exp2f)
  return __builtin_amdgcn_exp2f(x);
#else
  return exp2f(x);
#endif
}
__device__ __forceinline__ float frcp(float x) {
#if __has_builtin(__builtin_amdgcn_rcpf)
  return __builtin_amdgcn_rcpf(x);
#else
  return 1.0f / x;
#endif
}
__device__ __forceinline__ float fsigmoid(float z) {
  return frcp(1.0f + fexp2(z * -1.4426950408889634f));
}
__device__ __forceinline__ float fexp(float x) { return fexp2(x * 1.4426950408889634f); }

// ---------------------------------------------------------------------------
// Fused conversions: x_d, x_q, Vn[0..2]  (f32 -> bf16 elementwise)
// grid = 2188: [0,2048) xd | [2048,2176) xq | 4 blocks per Vn
// ---------------------------------------------------------------------------
__global__ void gmn_cvt_all(const float* __restrict__ xd, const float* __restrict__ xq,
                            const float* __restrict__ v0, const float* __restrict__ v1,
                            const float* __restrict__ v2, ushort* __restrict__ oxd,
                            ushort* __restrict__ oxq, ushort* __restrict__ ov0,
                            ushort* __restrict__ ov1, ushort* __restrict__ ov2) {
  int blk = blockIdx.x, tid = threadIdx.x;
  const float* src;
  ushort* dst;
  int i;
  if (blk < 2048) { src = xd; dst = oxd; i = blk * 256 + tid; }
  else if (blk < 2176) { src = xq; dst = oxq; i = (blk - 2048) * 256 + tid; }
  else if (blk < 2180) { src = v0; dst = ov0; i = (blk - 2176) * 256 + tid; }
  else if (blk < 2184) { src = v1; dst = ov1; i = (blk - 2180) * 256 + tid; }
  else { src = v2; dst = ov2; i = (blk - 2184) * 256 + tid; }
  *(ushort4*)(dst + (size_t)i * 4) = f4us4(F4C(src + (size_t)i * 4));
}

// ---------------------------------------------------------------------------
// Fused transpose+convert: W1,W2,W3,Wn[0..2] -> [bt][c][r] bf16. grid = 808.
// ---------------------------------------------------------------------------
__global__ __launch_bounds__(256) void gmn_t2bf_all(
    const float* __restrict__ W1, const float* __restrict__ W2,
    const float* __restrict__ W3, const float* __restrict__ Wn0,
    const float* __restrict__ Wn1, const float* __restrict__ Wn2,
    ushort* __restrict__ o1, ushort* __restrict__ o2, ushort* __restrict__ o3,
    ushort* __restrict__ on0, ushort* __restrict__ on1, ushort* __restrict__ on2) {
  __shared__ float tile[32][33];
  int blk = blockIdx.x;
  const float* in;
  ushort* out;
  int R, C, bt, t;
  if (blk < 8)        { in = W1;  out = o1;  R = 64;  C = 128; bt = 0; t = blk; }
  else if (blk < 24)  { in = W2;  out = o2;  R = 128; C = 128; bt = 0; t = blk - 8; }
  else if (blk < 40)  { in = W3;  out = o3;  R = 128; C = 128; bt = 0; t = blk - 24; }
  else if (blk < 296) { in = Wn0; out = on0; R = 128; C = 128; bt = (blk - 40) >> 4;  t = (blk - 40) & 15; }
  else if (blk < 552) { in = Wn1; out = on1; R = 128; C = 128; bt = (blk - 296) >> 4; t = (blk - 296) & 15; }
  else                { in = Wn2; out = on2; R = 128; C = 128; bt = (blk - 552) >> 4; t = (blk - 552) & 15; }
  int tilesC = C >> 5;
  int tr = t / tilesC, tc = t - tr * tilesC;
  int tx = threadIdx.x & 31, ty = threadIdx.x >> 5;
  const float* ib = in + (size_t)bt * R * C;
  ushort* ob = out + (size_t)bt * R * C;
#pragma unroll
  for (int i = 0; i < 4; ++i)
    tile[ty + i * 8][tx] = ib[(tr * 32 + ty + i * 8) * C + tc * 32 + tx];
  __syncthreads();
#pragma unroll
  for (int i = 0; i < 4; ++i)
    ob[(size_t)(tc * 32 + ty + i * 8) * R + tr * 32 + tx] = f2bf(tile[tx][ty + i * 8]);
}

// ---------------------------------------------------------------------------
// CSR construction (d and q merged into single dispatches)
// ---------------------------------------------------------------------------
__global__ void gmn_count_both(const int* __restrict__ dst_d, const int* __restrict__ dst_q,
                               int* __restrict__ cnt_d, int* __restrict__ cnt_q) {
  int i = blockIdx.x * 256 + threadIdx.x;
  if (i < cEd) atomicAdd(&cnt_d[dst_d[i]], 1);
  else atomicAdd(&cnt_q[dst_q[i - cEd]], 1);
}

// grid = 34: [0,32) data, [32,34) query. bsum[0..31]=data, bsum[32..33]=query
__global__ __launch_bounds__(1024) void gmn_scan_local_both(
    const int* __restrict__ cnt_d, const int* __restrict__ cnt_q,
    int* __restrict__ rp_d, int* __restrict__ rp_q, int* __restrict__ bsum) {
  __shared__ int sh[1024];
  int blk = blockIdx.x, tid = threadIdx.x;
  bool isQ = blk >= 32;
  const int* cnt = isQ ? cnt_q : cnt_d;
  int* rp = isQ ? rp_q : rp_d;
  int base = (isQ ? blk - 32 : blk) * 1024;
  int v = cnt[base + tid];
  sh[tid] = v;
  __syncthreads();
  for (int off = 1; off < 1024; off <<= 1) {
    int t = (tid >= off) ? sh[tid - off] : 0;
    __syncthreads();
    sh[tid] += t;
    __syncthreads();
  }
  rp[base + tid] = sh[tid] - v;  // exclusive
  if (tid == 1023) bsum[blk] = sh[1023];
}

// 64 threads; lanes [0,32) scan data block sums, lanes [32,34) scan query sums
__global__ void gmn_scan_off_both(int* __restrict__ bsum) {
  int l = threadIdx.x;
  bool valid = (l < 32) || (l >= 32 && l < 34);
  int v = valid ? bsum[l] : 0;
  int orig = v;
#pragma unroll
  for (int off = 1; off < 32; off <<= 1) {
    int t = __shfl_up(v, off, 32);
    if ((l & 31) >= off) v += t;
  }
  if (valid) bsum[l] = v - orig;  // exclusive within its group
}

__global__ __launch_bounds__(1024) void gmn_scan_add_both(int* __restrict__ rp_d,
                                                          int* __restrict__ rp_q,
                                                          const int* __restrict__ bsum) {
  int blk = blockIdx.x, tid = threadIdx.x;
  if (blk < 32) rp_d[blk * 1024 + tid] += bsum[blk];
  else rp_q[(blk - 32) * 1024 + tid] += bsum[blk];
}

__global__ void gmn_dinv_both(const int* __restrict__ cnt_d, const int* __restrict__ cnt_q,
                              float* __restrict__ dinv_d, float* __restrict__ dinv_q) {
  int i = blockIdx.x * 256 + threadIdx.x;
  if (i < cNd) dinv_d[i] = 1.0f / sqrtf((float)(cnt_d[i] + 1));
  else { int j = i - cNd; dinv_q[j] = 1.0f / sqrtf((float)(cnt_q[j] + 1)); }
}

__global__ void gmn_fill_both(const int* __restrict__ src_d, const int* __restrict__ dst_d,
                              const int* __restrict__ src_q, const int* __restrict__ dst_q,
                              const int* __restrict__ rp_d, const int* __restrict__ rp_q,
                              int* __restrict__ cur_d, int* __restrict__ cur_q,
                              int* __restrict__ col_d, int* __restrict__ col_q) {
  int i = blockIdx.x * 256 + threadIdx.x;
  if (i < cEd) {
    int d = dst_d[i];
    int p = atomicAdd(&cur_d[d], 1);
    col_d[rp_d[d] + p] = src_d[i];
  } else {
    int j = i - cEd;
    int d = dst_q[j];
    int p = atomicAdd(&cur_q[d], 1);
    col_q[rp_q[d] + p] = src_q[j];
  }
}

// ---------------------------------------------------------------------------
// Merged GCN dense (data rows [0,cNd) + query rows [cNd,cNd+cNq) of htmp):
// H[row][c] = bf16( dinv[row] * sum_d X[row][d] * W[d][c] ).  grid 544.
// ---------------------------------------------------------------------------
template <int KD>
__global__ __launch_bounds__(256) void gmn_gemm_merged(
    const ushort* __restrict__ Xd, const ushort* __restrict__ Xq,
    const ushort* __restrict__ WT, const float* __restrict__ dinv_d,
    const float* __restrict__ dinv_q, ushort* __restrict__ H) {
  int blk = blockIdx.x;
  int tid = threadIdx.x;
  int wave = tid >> 6, lane = tid & 63;
  int col = lane & 15, quad = lane >> 4;
  bool isQ = blk >= (cNd / 64);
  int mloc = (isQ ? blk - cNd / 64 : blk) * 64 + wave * 16;
  const ushort* X = isQ ? Xq : Xd;
  const float* dv = isQ ? dinv_q : dinv_d;
  size_t hbase = isQ ? (size_t)cNd : 0;
  floatx4 acc[8];
#pragma unroll
  for (int ct = 0; ct < 8; ++ct)
#pragma unroll
    for (int r = 0; r < 4; ++r) acc[ct][r] = 0.0f;
#pragma unroll
  for (int kc = 0; kc < KD / 32; ++kc) {
    bf16x8 a = *(const bf16x8*)(X + (size_t)(mloc + col) * KD + kc * 32 + quad * 8);
#pragma unroll
    for (int ct = 0; ct < 8; ++ct) {
      bf16x8 b = *(const bf16x8*)(WT + (size_t)(ct * 16 + col) * KD + kc * 32 + quad * 8);
      acc[ct] = __builtin_amdgcn_mfma_f32_16x16x32_bf16(a, b, acc[ct], 0, 0, 0);
    }
  }
  float sc[4];
#pragma unroll
  for (int r = 0; r < 4; ++r) sc[r] = dv[mloc + quad * 4 + r];
#pragma unroll
  for (int ct = 0; ct < 8; ++ct)
#pragma unroll
    for (int r = 0; r < 4; ++r)
      H[(hbase + mloc + quad * 4 + r) * 128 + ct * 16 + col] = f2bf(acc[ct][r] * sc[r]);
}

// ---------------------------------------------------------------------------
// Merged GCN aggregate: grid 4352: [0,4096) data (8 nodes/blk), rest query.
// ---------------------------------------------------------------------------
__global__ __launch_bounds__(256) void gmn_gather_merged(
    const ushort* __restrict__ htmp, const int* __restrict__ rp_d,
    const int* __restrict__ cnt_d, const int* __restrict__ col_d,
    const float* __restrict__ dinv_d, const int* __restrict__ rp_q,
    const int* __restrict__ cnt_q, const int* __restrict__ col_q,
    const float* __restrict__ dinv_q, const float* __restrict__ bias,
    ushort* __restrict__ dbf, ushort* __restrict__ qbf) {
  int blk = blockIdx.x, tid = threadIdx.x;
  bool isQ = blk >= (cNd / 8);
  int node = (isQ ? blk - cNd / 8 : blk) * 8 + (tid >> 5);
  int l = tid & 31;
  const ushort* hs = htmp + (isQ ? (size_t)cNd * 128 : 0);
  const int* rp = isQ ? rp_q : rp_d;
  const int* cnt = isQ ? cnt_q : cnt_d;
  const int* col = isQ ? col_q : col_d;
  const float* dinv = isQ ? dinv_q : dinv_d;
  ushort* outp = isQ ? qbf : dbf;
  int c = cnt[node], s0 = rp[node];
  float dt = dinv[node];
  float4 acc = us4f4(*(const ushort4*)(hs + (size_t)node * 128 + l * 4));
  int cm = c < 32 ? c : 32;
  for (int j0 = 0; j0 < cm; j0 += 8) {
    int ss[8];
    ushort4 v[8];
#pragma unroll
    for (int t = 0; t < 8; ++t) {
      int jj = j0 + t;
      ss[t] = col[s0 + (jj < c ? jj : c - 1)];
    }
#pragma unroll
    for (int t = 0; t < 8; ++t)
      v[t] = *(const ushort4*)(hs + (size_t)ss[t] * 128 + l * 4);
#pragma unroll
    for (int t = 0; t < 8; ++t) {
      if (j0 + t < cm) {
        float4 f = us4f4(v[t]);
        acc.x += f.x; acc.y += f.y; acc.z += f.z; acc.w += f.w;
      }
    }
  }
  for (int j = 32; j < c; ++j) {
    int s = col[s0 + j];
    float4 f = us4f4(*(const ushort4*)(hs + (size_t)s * 128 + l * 4));
    acc.x += f.x; acc.y += f.y; acc.z += f.z; acc.w += f.w;
  }
  float4 bv = F4C(bias + l * 4);
  float4 r;
  r.x = fmaxf(acc.x * dt + bv.x, 0.0f);
  r.y = fmaxf(acc.y * dt + bv.y, 0.0f);
  r.z = fmaxf(acc.z * dt + bv.z, 0.0f);
  r.w = fmaxf(acc.w * dt + bv.w, 0.0f);
  *(ushort4*)(outp + (size_t)node * 128 + l * 4) = f4us4(r);
}

// ---------------------------------------------------------------------------
// Fused level prep: grid 1792 = qw[0,1024) | logits[1024,1536) | ld[1536,1664)
// | lq[1664,1792).  All MFMA except lq (tiny rowdot).
// ---------------------------------------------------------------------------
__global__ __launch_bounds__(256) void gmn_prep(
    const ushort* __restrict__ qbf, const ushort* __restrict__ dbf,
    const ushort* __restrict__ wnT, const ushort* __restrict__ vnbf,
    const float* __restrict__ Vn, ushort* __restrict__ qw,
    float* __restrict__ lgt, float* __restrict__ ldb, float* __restrict__ lqb) {
  __shared__ float sh_r[16 * 132];
  __shared__ float sh_v[16 * 132];
  int blk = blockIdx.x, tid = threadIdx.x;
  int wave = tid >> 6, lane = tid & 63;
  int col = lane & 15, quad = lane >> 4;

  if (blk < 1024) {  // ---- qW[b,k] = q[b] @ Wn[k] ----
    int b = blk >> 4, k = blk & 15;
    int et0 = wave * 2;
    floatx4 acc[2][2];
#pragma unroll
    for (int qt = 0; qt < 2; ++qt)
#pragma unroll
      for (int ei = 0; ei < 2; ++ei)
#pragma unroll
        for (int r = 0; r < 4; ++r) acc[qt][ei][r] = 0.0f;
#pragma unroll
    for (int kc = 0; kc < 4; ++kc) {
      bf16x8 a0 = *(const bf16x8*)(qbf + (size_t)(b * 32 + col) * 128 + kc * 32 + quad * 8);
      bf16x8 a1 = *(const bf16x8*)(qbf + (size_t)(b * 32 + 16 + col) * 128 + kc * 32 + quad * 8);
#pragma unroll
      for (int ei = 0; ei < 2; ++ei) {
        bf16x8 bf = *(const bf16x8*)(wnT + (size_t)(k * 128 + (et0 + ei) * 16 + col) * 128 +
                                     kc * 32 + quad * 8);
        acc[0][ei] = __builtin_amdgcn_mfma_f32_16x16x32_bf16(a0, bf, acc[0][ei], 0, 0, 0);
        acc[1][ei] = __builtin_amdgcn_mfma_f32_16x16x32_bf16(a1, bf, acc[1][ei], 0, 0, 0);
      }
    }
#pragma unroll
    for (int qt = 0; qt < 2; ++qt)
#pragma unroll
      for (int ei = 0; ei < 2; ++ei)
#pragma unroll
        for (int r = 0; r < 4; ++r)
          qw[((size_t)(b * 16 + k) << 12) + (qt * 16 + quad * 4 + r) * 128 +
             (et0 + ei) * 16 + col] = f2bf(acc[qt][ei][r]);
  } else if (blk < 1536) {  // ---- logits (raw, scaled) ----
    int b2 = blk - 1024;
    int b = b2 >> 3, nc = b2 & 7;
    int n = nc * 64 + wave * 16 + col;
    floatx4 acc[2];
#pragma unroll
    for (int qt = 0; qt < 2; ++qt)
#pragma unroll
      for (int r = 0; r < 4; ++r) acc[qt][r] = 0.0f;
#pragma unroll
    for (int kc = 0; kc < 4; ++kc) {
      bf16x8 bf = *(const bf16x8*)(dbf + ((size_t)(b * 512 + n) << 7) + kc * 32 + quad * 8);
      bf16x8 a0 = *(const bf16x8*)(qbf + (size_t)(b * 32 + col) * 128 + kc * 32 + quad * 8);
      bf16x8 a1 = *(const bf16x8*)(qbf + (size_t)(b * 32 + 16 + col) * 128 + kc * 32 + quad * 8);
      acc[0] = __builtin_amdgcn_mfma_f32_16x16x32_bf16(a0, bf, acc[0], 0, 0, 0);
      acc[1] = __builtin_amdgcn_mfma_f32_16x16x32_bf16(a1, bf, acc[1], 0, 0, 0);
    }
    const float sc = 1.0f / sqrtf(128.0f);
#pragma unroll
    for (int qt = 0; qt < 2; ++qt)
#pragma unroll
      for (int r = 0; r < 4; ++r)
        lgt[((size_t)(b * 32 + qt * 16 + quad * 4 + r) << 9) + n] = acc[qt][r] * sc;
  } else if (blk < 1664) {  // ---- ld[b,k,n] = d · Vn[k][128:] ----
    int b3 = blk - 1536;
    int b = b3 >> 1, half = b3 & 1;
    bf16x8 bfr[4];
#pragma unroll
    for (int kc = 0; kc < 4; ++kc)
      bfr[kc] = *(const bf16x8*)(vnbf + col * 256 + 128 + kc * 32 + quad * 8);
#pragma unroll
    for (int i = 0; i < 4; ++i) {
      int mt = half * 16 + wave * 4 + i;
      floatx4 acc;
#pragma unroll
      for (int r = 0; r < 4; ++r) acc[r] = 0.0f;
#pragma unroll
      for (int kc = 0; kc < 4; ++kc) {
        bf16x8 a = *(const bf16x8*)(dbf + ((size_t)(b * 512 + mt * 16 + col) << 7) +
                                    kc * 32 + quad * 8);
        acc = __builtin_amdgcn_mfma_f32_16x16x32_bf16(a, bfr[kc], acc, 0, 0, 0);
      }
#pragma unroll
      for (int r = 0; r < 4; ++r)
        ldb[((size_t)(b * 16 + col) << 9) + mt * 16 + quad * 4 + r] = acc[r];
    }
  } else {  // ---- lq rowdot from bf16 q ----
    int b4 = blk - 1664;
    int g0 = b4 * 16;
#pragma unroll
    for (int i = 0; i < 8; ++i) {
      int j = tid + 256 * i;
      int a = j >> 7, e = j & 127;
      sh_r[a * 132 + e] = bf2f(qbf[(size_t)(g0 + a) * 128 + e]);
      sh_v[a * 132 + e] = Vn[a * 256 + e];
    }
    __syncthreads();
    int r = tid & 15, k = tid >> 4;
    float s = 0.0f;
#pragma unroll 8
    for (int e = 0; e < 128; ++e) s += sh_r[r * 132 + e] * sh_v[k * 132 + e];
    int g = g0 + r;
    int b = g >> 5, rr = g & 31;
    lqb[((b * 16 + k) << 5) + rr] = s;
  }
}

// ---------------------------------------------------------------------------
// MFMA NTN level kernel, split-k x2 (unchanged from R4).
// ---------------------------------------------------------------------------
__global__ __launch_bounds__(256, 4) void gmn_level_mfma(
    const ushort* __restrict__ qw, const ushort* __restrict__ dbf,
    const float* __restrict__ lqb, const float* __restrict__ ldb,
    const float* __restrict__ bn, const float* __restrict__ cw,
    const float* __restrict__ w_end, int o1, int o2, int do_facc,
    float* __restrict__ Ebuf, float* __restrict__ Fbuf) {
  __shared__ float s_ld[8 * 64];
  __shared__ float s_lq[8 * 32];
  int tid = threadIdx.x;
  int wave = tid >> 6, lane = tid & 63;
  int kh = blockIdx.x & 1;
  int rest = blockIdx.x >> 1;
  int b = rest >> 3, nc = rest & 7;
  int k0 = kh * 8;
  int col = lane & 15, quad = lane >> 4;
  int nn = wave * 16 + col;
  int n = nc * 64 + nn;

#pragma unroll
  for (int i = 0; i < 2; ++i) {
    int j = tid + 256 * i;
    int kk = j >> 6, nl = j & 63;
    s_ld[j] = ldb[((b * 16 + k0 + kk) << 9) + nc * 64 + nl];
  }
  {
    int kk = tid >> 5, qq = tid & 31;
    s_lq[tid] = lqb[(b * 16 + k0 + kk) * 32 + qq];
  }
  __syncthreads();

  float bnk[8], cwk[8], wkk[8];
#pragma unroll
  for (int kk = 0; kk < 8; ++kk) {
    bnk[kk] = bn[k0 + kk];
    cwk[kk] = cw[k0 + kk];
    float w = 0.0f;
    if (do_facc) {
      w = w_end[o1 + k0 + kk];
      if (o2 >= 0) w += w_end[o2 + k0 + kk];
    }
    wkk[kk] = w;
  }

  const ushort* dptr = dbf + (((size_t)(b * 512 + n)) << 7) + quad * 8;
  bf16x8 bfr[4];
#pragma unroll
  for (int kc = 0; kc < 4; ++kc) bfr[kc] = *(const bf16x8*)(dptr + kc * 32);

  const ushort* qwb = qw + ((size_t)b << 16) + (k0 << 12) + quad * 8;
  floatx4 eacc[2], facc[2];
#pragma unroll
  for (int t = 0; t < 2; ++t)
#pragma unroll
    for (int r = 0; r < 4; ++r) { eacc[t][r] = 0.0f; facc[t][r] = 0.0f; }

#pragma unroll 2
  for (int kk = 0; kk < 8; ++kk) {
    const ushort* qk = qwb + (kk << 12);
    floatx4 bil[2];
#pragma unroll
    for (int t = 0; t < 2; ++t)
#pragma unroll
      for (int r = 0; r < 4; ++r) bil[t][r] = 0.0f;
#pragma unroll
    for (int kc = 0; kc < 4; ++kc) {
      bf16x8 a0 = *(const bf16x8*)(qk + (col << 7) + kc * 32);
      bf16x8 a1 = *(const bf16x8*)(qk + ((col + 16) << 7) + kc * 32);
      bil[0] = __builtin_amdgcn_mfma_f32_16x16x32_bf16(a0, bfr[kc], bil[0], 0, 0, 0);
      bil[1] = __builtin_amdgcn_mfma_f32_16x16x32_bf16(a1, bfr[kc], bil[1], 0, 0, 0);
    }
    float ldv = s_ld[kk * 64 + nn] + bnk[kk];
#pragma unroll
    for (int t = 0; t < 2; ++t) {
#pragma unroll
      for (int r = 0; r < 4; ++r) {
        float lqv = s_lq[kk * 32 + t * 16 + quad * 4 + r];
        float sg = fsigmoid(bil[t][r] + lqv + ldv);
        eacc[t][r] += cwk[kk] * sg;
        facc[t][r] += wkk[kk] * sg;
      }
    }
  }

  float* Ep = Ebuf + (size_t)kh * cSZ;
  float* Fp = Fbuf + (size_t)kh * cSZ;
#pragma unroll
  for (int t = 0; t < 2; ++t) {
#pragma unroll
    for (int r = 0; r < 4; ++r) {
      size_t idx = ((size_t)(b * 32 + t * 16 + quad * 4 + r) << 9) + n;
      Ep[idx] = eacc[t][r];
      if (do_facc) Fp[idx] = facc[t][r];
    }
  }
}

// ---------------------------------------------------------------------------
// combine: a = softmax_row(lgt); v = a*(E0+E1); f = a*(F0+F1);
// t = w*(do_sm ? softmax_row(v) : v) + f
// mode 0: accb = t | mode 1: accb += t | mode 2: out = softmax_row(accb+t+be)
// ---------------------------------------------------------------------------
__global__ __launch_bounds__(256) void gmn_combine2(
    const float* __restrict__ lgt, const float* __restrict__ Ebuf,
    const float* __restrict__ Fbuf, float* __restrict__ accb,
    const float* __restrict__ w_end, const float* __restrict__ b_end,
    int widx, int do_sm, int hasF, int mode, float* __restrict__ out) {
  __shared__ float sh[8];
  int tid = threadIdx.x;
  size_t base = (size_t)blockIdx.x * 512;
  size_t i0 = base + tid, i1 = i0 + 256;
  float w = w_end[widx];
  float l0 = lgt[i0], l1 = lgt[i1];
  // softmax(att)
  float m = fmaxf(l0, l1);
#pragma unroll
  for (int o = 32; o; o >>= 1) m = fmaxf(m, __shfl_xor(m, o, 64));
  if ((tid & 63) == 0) sh[tid >> 6] = m;
  __syncthreads();
  m = fmaxf(fmaxf(sh[0], sh[1]), fmaxf(sh[2], sh[3]));
  float e0 = fexp(l0 - m), e1 = fexp(l1 - m);
  float s = e0 + e1;
#pragma unroll
  for (int o = 32; o; o >>= 1) s += __shfl_xor(s, o, 64);
  if ((tid & 63) == 0) sh[4 + (tid >> 6)] = s;
  __syncthreads();
  s = sh[4] + sh[5] + sh[6] + sh[7];
  float ainv = frcp(s);
  float a0 = e0 * ainv, a1 = e1 * ainv;
  __syncthreads();
  float v0 = a0 * (Ebuf[i0] + Ebuf[i0 + cSZ]);
  float v1 = a1 * (Ebuf[i1] + Ebuf[i1 + cSZ]);
  float f0 = 0.0f, f1 = 0.0f;
  if (hasF) {
    f0 = a0 * (Fbuf[i0] + Fbuf[i0 + cSZ]);
    f1 = a1 * (Fbuf[i1] + Fbuf[i1 + cSZ]);
  }
  if (do_sm) {
    float mm = fmaxf(v0, v1);
#pragma unroll
    for (int o = 32; o; o >>= 1) mm = fmaxf(mm, __shfl_xor(mm, o, 64));
    if ((tid & 63) == 0) sh[tid >> 6] = mm;
    __syncthreads();
    mm = fmaxf(fmaxf(sh[0], sh[1]), fmaxf(sh[2], sh[3]));
    float ee0 = fexp(v0 - mm), ee1 = fexp(v1 - mm);
    float ss = ee0 + ee1;
#pragma unroll
    for (int o = 32; o; o >>= 1) ss += __shfl_xor(ss, o, 64);
    if ((tid & 63) == 0) sh[4 + (tid >> 6)] = ss;
    __syncthreads();
    ss = sh[4] + sh[5] + sh[6] + sh[7];
    float inv = frcp(ss);
    v0 = ee0 * inv;
    v1 = ee1 * inv;
    __syncthreads();
  }
  float t0 = w * v0 + f0, t1 = w * v1 + f1;
  if (mode == 0) {
    accb[i0] = t0;
    accb[i1] = t1;
  } else if (mode == 1) {
    accb[i0] += t0;
    accb[i1] += t1;
  } else {
    float be = b_end[0];
    float z0 = accb[i0] + t0 + be, z1 = accb[i1] + t1 + be;
    float mm = fmaxf(z0, z1);
#pragma unroll
    for (int o = 32; o; o >>= 1) mm = fmaxf(mm, __shfl_xor(mm, o, 64));
    if ((tid & 63) == 0) sh[tid >> 6] = mm;
    __syncthreads();
    mm = fmaxf(fmaxf(sh[0], sh[1]), fmaxf(sh[2], sh[3]));
    float ee0 = fexp(z0 - mm), ee1 = fexp(z1 - mm);
    float ss = ee0 + ee1;
#pragma unroll
    for (int o = 32; o; o >>= 1) ss += __shfl_xor(ss, o, 64);
    if ((tid & 63) == 0) sh[4 + (tid >> 6)] = ss;
    __syncthreads();
    ss = sh[4] + sh[5] + sh[6] + sh[7];
    float inv = frcp(ss);
    out[i0] = ee0 * inv;
    out[i1] = ee1 * inv;
  }
}

// ---------------------------------------------------------------------------
// Host orchestration (24 dispatches total)
// ---------------------------------------------------------------------------
extern "C" void kernel_launch(void* const* d_in, const int* in_sizes, int n_in,
                              void* d_out, int out_size, void* d_ws, size_t ws_size,
                              hipStream_t stream) {
  (void)in_sizes; (void)n_in; (void)out_size; (void)ws_size;
  const float* x_d = (const float*)d_in[0];
  const float* x_q = (const float*)d_in[1];
  const int* ei_d = (const int*)d_in[2];
  const int* ei_q = (const int*)d_in[3];
  const float* W1 = (const float*)d_in[6];
  const float* b1 = (const float*)d_in[7];
  const float* W2 = (const float*)d_in[8];
  const float* b2 = (const float*)d_in[9];
  const float* W3 = (const float*)d_in[10];
  const float* b3 = (const float*)d_in[11];
  const float* Wn[3] = {(const float*)d_in[12], (const float*)d_in[17], (const float*)d_in[22]};
  const float* Vn[3] = {(const float*)d_in[13], (const float*)d_in[18], (const float*)d_in[23]};
  const float* bn[3] = {(const float*)d_in[14], (const float*)d_in[19], (const float*)d_in[24]};
  const float* cw[3] = {(const float*)d_in[15], (const float*)d_in[20], (const float*)d_in[25]};
  const float* w_end = (const float*)d_in[27];
  const float* b_end = (const float*)d_in[28];
  float* out = (float*)d_out;

  char* wsp = (char*)d_ws;
  auto alloc = [&](size_t nbytes) {
    void* p = (void*)wsp;
    wsp += (nbytes + 255) & ~(size_t)255;
    return p;
  };
  // cnt_d,cnt_q,cur_d,cur_q contiguous -> single memset
  int* cnt_d = (int*)alloc(cNd * 4);
  int* cnt_q = (int*)alloc(cNq * 4);
  int* cur_d = (int*)alloc(cNd * 4);
  int* cur_q = (int*)alloc(cNq * 4);
  float* dinv_d = (float*)alloc(cNd * 4);
  float* dinv_q = (float*)alloc(cNq * 4);
  int* rp_d = (int*)alloc(cNd * 4);
  int* rp_q = (int*)alloc(cNq * 4);
  int* col_d = (int*)alloc((size_t)cEd * 4);
  int* col_q = (int*)alloc((size_t)cEq * 4);
  int* bsum = (int*)alloc(64 * 4);
  ushort* xdbf = (ushort*)alloc((size_t)cNd * 64 * 2);
  ushort* xqbf = (ushort*)alloc((size_t)cNq * 64 * 2);
  ushort* w1T = (ushort*)alloc(128 * 64 * 2);
  ushort* w2T = (ushort*)alloc(128 * 128 * 2);
  ushort* w3T = (ushort*)alloc(128 * 128 * 2);
  ushort* wnT[3];
  for (int l = 0; l < 3; ++l) wnT[l] = (ushort*)alloc((size_t)16 * 128 * 128 * 2);
  ushort* vnbf[3];
  for (int l = 0; l < 3; ++l) vnbf[l] = (ushort*)alloc(16 * 256 * 2);
  ushort* htmp = (ushort*)alloc((size_t)(cNd + cNq) * 128 * 2);
  ushort* dbf = (ushort*)alloc((size_t)cNd * 128 * 2);
  ushort* qbf[3];
  for (int l = 0; l < 3; ++l) qbf[l] = (ushort*)alloc((size_t)cNq * 128 * 2);
  float* lgt = (float*)alloc(cSZ * 4);
  float* Ebuf = (float*)alloc(cSZ * 2 * 4);
  float* Fbuf = (float*)alloc(cSZ * 2 * 4);
  float* accb = (float*)alloc(cSZ * 4);
  float* lqb = (float*)alloc((size_t)cB * 16 * 32 * 4);
  float* ldb = (float*)alloc((size_t)cB * 16 * 512 * 4);
  ushort* qwbuf = (ushort*)alloc((size_t)cB * 16 * 32 * 128 * 2);

  const int* src_d = ei_d;
  const int* dst_d = ei_d + cEd;
  const int* src_q = ei_q;
  const int* dst_q = ei_q + cEq;

  hipMemsetAsync(cnt_d, 0, (size_t)2 * (cNd + cNq) * 4, stream);  // cnt+cur both sides

  // --- conversions (2 dispatches) ---
  gmn_cvt_all<<<2188, 256, 0, stream>>>(x_d, x_q, Vn[0], Vn[1], Vn[2], xdbf, xqbf,
                                        vnbf[0], vnbf[1], vnbf[2]);
  gmn_t2bf_all<<<808, 256, 0, stream>>>(W1, W2, W3, Wn[0], Wn[1], Wn[2], w1T, w2T, w3T,
                                        wnT[0], wnT[1], wnT[2]);

  // --- CSR (6 dispatches) ---
  gmn_count_both<<<(cEd + cEq) / 256, 256, 0, stream>>>(dst_d, dst_q, cnt_d, cnt_q);
  gmn_scan_local_both<<<34, 1024, 0, stream>>>(cnt_d, cnt_q, rp_d, rp_q, bsum);
  gmn_scan_off_both<<<1, 64, 0, stream>>>(bsum);
  gmn_scan_add_both<<<34, 1024, 0, stream>>>(rp_d, rp_q, bsum);
  gmn_dinv_both<<<(cNd + cNq) / 256, 256, 0, stream>>>(cnt_d, cnt_q, dinv_d, dinv_q);
  gmn_fill_both<<<(cEd + cEq) / 256, 256, 0, stream>>>(src_d, dst_d, src_q, dst_q, rp_d,
                                                       rp_q, cur_d, cur_q, col_d, col_q);

  const ushort* wT[3] = {w1T, w2T, w3T};
  const float* bias[3] = {b1, b2, b3};
  const int o1s[3] = {0, 19, 3};
  const int o2s[3] = {-1, -1, 35};
  const int dofac[3] = {0, 1, 1};
  const int dosms[3] = {1, 0, 1};
  const int modes[3] = {0, 1, 2};

  for (int l = 0; l < 3; ++l) {
    // merged GCN layer l (data + query)
    if (l == 0)
      gmn_gemm_merged<64><<<(cNd + cNq) / 64, 256, 0, stream>>>(xdbf, xqbf, w1T, dinv_d,
                                                                dinv_q, htmp);
    else
      gmn_gemm_merged<128><<<(cNd + cNq) / 64, 256, 0, stream>>>(dbf, qbf[l - 1], wT[l],
                                                                 dinv_d, dinv_q, htmp);
    gmn_gather_merged<<<(cNd + cNq) / 8, 256, 0, stream>>>(htmp, rp_d, cnt_d, col_d,
                                                           dinv_d, rp_q, cnt_q, col_q,
                                                           dinv_q, bias[l], dbf, qbf[l]);
    // level l
    gmn_prep<<<1792, 256, 0, stream>>>(qbf[l], dbf, wnT[l], vnbf[l], Vn[l], qwbuf, lgt,
                                       ldb, lqb);
    gmn_level_mfma<<<cB * 8 * 2, 256, 0, stream>>>(qwbuf, dbf, lqb, ldb, bn[l], cw[l],
                                                   w_end, o1s[l], o2s[l], dofac[l],
                                                   Ebuf, Fbuf);
    gmn_combine2<<<cB * cNQ, 256, 0, stream>>>(lgt, Ebuf, Fbuf, accb, w_end, b_end, l,
                                               dosms[l], dofac[l], modes[l], out);
  }
}